// Round 3
// baseline (431.664 us; speedup 1.0000x reference)
//
#include <hip/hip_runtime.h>
#include <cstdint>
#include <cstddef>

#define CCLS 5994
#define CPAD 6016
#define BATCH 8192
#define KDIM 192
#define EMAX 24

#define S_SC 30.0f
#define COSM 0.9800665778412416f
#define SINM 0.19866933079506122f
#define THC  0.9800665778412416f
#define MMC  0.039733866159012244f

typedef __attribute__((ext_vector_type(8))) short short8;
typedef __attribute__((ext_vector_type(4))) float f32x4;
typedef unsigned short u16;
typedef unsigned int u32;

__device__ __forceinline__ u16 f2bf(float f) {
  u32 u = __float_as_uint(f);
  u32 r = (u + 0x7FFFu + ((u >> 16) & 1u)) >> 16;
  return (u16)r;
}

__device__ __forceinline__ float arc_phi(float c) {
  float s2 = fminf(fmaxf(1.0f - c * c, 0.0f), 1.0f);
  float sine = sqrtf(s2);
  return (c - THC > 0.0f) ? (c - MMC) : (c * COSM - sine * SINM);
}

__device__ __forceinline__ float shift_of(float vmax) {
  return (2.0f - vmax) * (1.0f + 2.0f / vmax);
}

__device__ __forceinline__ float wave_sum(float v) {
#pragma unroll
  for (int off = 1; off < 64; off <<= 1) v += __shfl_xor(v, off);
  return v;
}

// ---------------- fast zero (replaces pathological hipMemsetAsync fill) ----------------
__global__ void zero_k(f32x4* __restrict__ p, int n4) {
  const int i = blockIdx.x * 256 + threadIdx.x;
  if (i < n4) p[i] = (f32x4){0.f, 0.f, 0.f, 0.f};
}

// ---------------- fused: normalize w -> wb | normalize x -> xb + segment sums + inverse lists ----------------
__global__ void prep_k(const float* __restrict__ x, const float* __restrict__ w,
                       const int* __restrict__ label,
                       u16* __restrict__ xb, u16* __restrict__ wb,
                       float* __restrict__ sumx, float* __restrict__ cnts,
                       int* __restrict__ ecnt, int* __restrict__ eidx) {
  const int bid = blockIdx.x;
  const int lane = threadIdx.x & 63;
  const int sub = threadIdx.x >> 6;
  if (bid < CPAD / 4) {
    const int row = bid * 4 + sub;
    float v0 = 0.f, v1 = 0.f, v2 = 0.f;
    if (row < CCLS) {
      const float* p = w + (size_t)row * KDIM;
      v0 = p[lane]; v1 = p[lane + 64]; v2 = p[lane + 128];
    }
    float ss = wave_sum(v0 * v0 + v1 * v1 + v2 * v2);
    float inv = 1.0f / fmaxf(sqrtf(ss), 1e-12f);
    if (row >= CCLS) inv = 0.f;
    u16* q = wb + (size_t)row * KDIM;
    q[lane] = f2bf(v0 * inv);
    q[lane + 64] = f2bf(v1 * inv);
    q[lane + 128] = f2bf(v2 * inv);
  } else {
    const int row = (bid - CPAD / 4) * 4 + sub;
    const float* p = x + (size_t)row * KDIM;
    float v0 = p[lane], v1 = p[lane + 64], v2 = p[lane + 128];
    float ss = wave_sum(v0 * v0 + v1 * v1 + v2 * v2);
    float inv = 1.0f / fmaxf(sqrtf(ss), 1e-12f);
    float n0 = v0 * inv, n1 = v1 * inv, n2 = v2 * inv;
    u16* q = xb + (size_t)row * KDIM;
    q[lane] = f2bf(n0); q[lane + 64] = f2bf(n1); q[lane + 128] = f2bf(n2);
    const int lab = label[row];
    float* sp = sumx + (size_t)lab * KDIM;
    atomicAdd(&sp[lane], n0);
    atomicAdd(&sp[lane + 64], n1);
    atomicAdd(&sp[lane + 128], n2);
    if (lane == 0) {
      atomicAdd(&cnts[lab], 1.0f);
      if (row >= CCLS) {
        int pos = atomicAdd(&ecnt[lab], 1);
        if (pos < EMAX) eidx[lab * EMAX + pos] = row;
      }
    }
  }
}

// ---------------- class means -> bf16 (padded rows zeroed) ----------------
__global__ void mean_k(const float* __restrict__ sumx, const float* __restrict__ cnts,
                       u16* __restrict__ mb) {
  const int row = blockIdx.x * 4 + (threadIdx.x >> 6);
  const int lane = threadIdx.x & 63;
  u16* q = mb + (size_t)row * KDIM;
  if (row < CCLS) {
    const float inv = 1.0f / cnts[row];
    const float* sp = sumx + (size_t)row * KDIM;
    q[lane] = f2bf(sp[lane] * inv);
    q[lane + 64] = f2bf(sp[lane + 64] * inv);
    q[lane + 128] = f2bf(sp[lane + 128] * inv);
  } else {
    q[lane] = 0; q[lane + 64] = 0; q[lane + 128] = 0;
  }
}

// ---------------- double-buffered 128x128 K=192 GEMM core ----------------
__device__ __forceinline__ void gemm_core(const u16* __restrict__ A, const u16* __restrict__ Bm,
                                          int row0, int col0, int wid, int lane,
                                          u16 (*As)[8192], u16 (*Bs)[8192],
                                          f32x4 (&acc)[4][4]) {
  const int wm = wid >> 1, wn = wid & 1;
  auto stage = [&](int buf, int k0) {
#pragma unroll
    for (int i = 0; i < 4; ++i) {
      const int c = wid * 4 + i;              // chunk 0..15, 1024B each
      const int r = c * 8 + (lane >> 3);      // tile row 0..127
      const int cc = (lane & 7) * 8;          // tile col (bf16)
      const u16* ga = A + (size_t)(row0 + r) * KDIM + (k0 + cc);
      const u16* gb = Bm + (size_t)(col0 + r) * KDIM + (k0 + cc);
      __builtin_amdgcn_global_load_lds((const __attribute__((address_space(1))) void*)ga,
                                       (__attribute__((address_space(3))) void*)(&As[buf][c * 512]),
                                       16, 0, 0);
      __builtin_amdgcn_global_load_lds((const __attribute__((address_space(1))) void*)gb,
                                       (__attribute__((address_space(3))) void*)(&Bs[buf][c * 512]),
                                       16, 0, 0);
    }
  };
  auto compute = [&](int buf) {
#pragma unroll
    for (int kk = 0; kk < 2; ++kk) {
      short8 af[4], bf[4];
#pragma unroll
      for (int mi = 0; mi < 4; ++mi)
        af[mi] = *(const short8*)&As[buf][(wm * 64 + mi * 16 + (lane & 15)) * 64 + kk * 32 + (lane >> 4) * 8];
#pragma unroll
      for (int ni = 0; ni < 4; ++ni)
        bf[ni] = *(const short8*)&Bs[buf][(wn * 64 + ni * 16 + (lane & 15)) * 64 + kk * 32 + (lane >> 4) * 8];
#pragma unroll
      for (int mi = 0; mi < 4; ++mi)
#pragma unroll
        for (int ni = 0; ni < 4; ++ni)
          acc[mi][ni] = __builtin_amdgcn_mfma_f32_16x16x32_bf16(af[mi], bf[ni], acc[mi][ni], 0, 0, 0);
    }
  };

  stage(0, 0);
  asm volatile("s_waitcnt vmcnt(0)" ::: "memory");
  __syncthreads();
  stage(1, 64);
  compute(0);
  asm volatile("s_waitcnt vmcnt(0)" ::: "memory");
  __syncthreads();
  stage(0, 128);
  compute(1);
  asm volatile("s_waitcnt vmcnt(0)" ::: "memory");
  __syncthreads();
  compute(0);
}

// ---------------- mega1: z=0 sample GEMM+ArcFace+CE | z=1 center GEMM+ArcFace+CE+dup | z=2 Gram stats pass1 ----------------
__launch_bounds__(256)
__global__ void mega1_k(const u16* __restrict__ xb, const u16* __restrict__ wb,
                        const u16* __restrict__ mb, const int* __restrict__ label,
                        float* __restrict__ out1, float* __restrict__ out2,
                        float* __restrict__ scal,
                        float* __restrict__ rowse_s, float* __restrict__ rowsum_s,
                        float* __restrict__ rowtgt_s,
                        float* __restrict__ rowse_c, float* __restrict__ rowsum_c,
                        float* __restrict__ rowtgt_c,
                        const int* __restrict__ ecnt, const int* __restrict__ eidx) {
  const int MODE = blockIdx.z;
  const int bx = blockIdx.x, by = blockIdx.y;
  if (MODE >= 1 && by >= 47) return;
  if (MODE == 2 && by > bx) return;  // symmetric Gram: upper-tri only

  __shared__ u16 As[2][8192];
  __shared__ u16 Bs[2][8192];
  float* red = (float*)As;  // aliased; used only after a barrier past the last As read

  const int tid = threadIdx.x;
  const int lane = tid & 63;
  const int wid = tid >> 6;
  const int row0 = by * 128;
  const int col0 = bx * 128;
  const int wm = wid >> 1, wn = wid & 1;

  const u16* A = (MODE == 0) ? xb : mb;
  const u16* Bm = (MODE == 2) ? mb : wb;

  f32x4 acc[4][4];
#pragma unroll
  for (int i = 0; i < 4; ++i)
#pragma unroll
    for (int j = 0; j < 4; ++j)
      acc[i][j] = (f32x4){0.f, 0.f, 0.f, 0.f};

  gemm_core(A, Bm, row0, col0, wid, lane, As, Bs, acc);

  const int rl = (lane >> 4) * 4;  // C/D: row = (lane>>4)*4 + reg, col = lane&15
  const int cl = lane & 15;

  if (MODE <= 1) {
    float* outp = (MODE == 0) ? out1 : out2;
    float* rse = (MODE == 0) ? rowse_s : rowse_c;
    float* rsm = (MODE == 0) ? rowsum_s : rowsum_c;
    float* rtg = (MODE == 0) ? rowtgt_s : rowtgt_c;
#pragma unroll
    for (int mi = 0; mi < 4; ++mi) {
#pragma unroll
      for (int r = 0; r < 4; ++r) {
        const int gr = row0 + wm * 64 + mi * 16 + rl + r;  // uniform across 16-lane group
        if (MODE == 1 && gr >= CCLS) continue;
        const int tgt = (MODE == 0) ? label[gr] : gr;
        int ec = 0;
        if (MODE == 1) ec = min(ecnt[gr], EMAX);
        float se = 0.f, sm = 0.f;
#pragma unroll
        for (int ni = 0; ni < 4; ++ni) {
          const int gc = col0 + wn * 64 + ni * 16 + cl;
          if (gc < CCLS) {
            float v = acc[mi][ni][r];
            float val = ((gc == tgt) ? arc_phi(v) : v) * S_SC;
            outp[(size_t)gr * CCLS + gc] = val;
            if (MODE == 1)
              for (int k = 0; k < ec; ++k)
                out2[(size_t)eidx[gr * EMAX + k] * CCLS + gc] = val;
            se += __expf(val - 30.0f);
            sm += val;
            if (gc == tgt) rtg[gr] = val;  // unique writer
          }
        }
#pragma unroll
        for (int m = 1; m < 16; m <<= 1) {
          se += __shfl_xor(se, m);
          sm += __shfl_xor(sm, m);
        }
        if (cl == 0) {
          atomicAdd(&rse[gr], se);
          atomicAdd(&rsm[gr], sm);
        }
      }
    }
  } else {
    float lsum = 0.f;
    float lmax = -3.0e38f;
#pragma unroll
    for (int mi = 0; mi < 4; ++mi)
#pragma unroll
      for (int r = 0; r < 4; ++r) {
        const int gi = row0 + wm * 64 + mi * 16 + rl + r;
#pragma unroll
        for (int ni = 0; ni < 4; ++ni) {
          const int gj = col0 + wn * 64 + ni * 16 + cl;
          if (gi < CCLS && gj < CCLS && gi != gj) {
            float g = 2.0f * acc[mi][ni][r];
            lsum += __expf(g - 2.0f);
            lmax = fmaxf(lmax, g);
          }
        }
      }
    const float wgt = (bx == by) ? 1.0f : 2.0f;
    lsum = wave_sum(lsum) * wgt;
#pragma unroll
    for (int off = 1; off < 64; off <<= 1) lmax = fmaxf(lmax, __shfl_xor(lmax, off));
    __syncthreads();  // all As reads done before aliased red writes
    if (lane == 0) { red[wid] = lsum; red[4 + wid] = lmax; }
    __syncthreads();
    if (tid == 0) {
      atomicAdd(&scal[1], red[0] + red[1] + red[2] + red[3]);
      float m = fmaxf(fmaxf(red[4], red[5]), fmaxf(red[6], red[7]));
      u32 b = __float_as_uint(m);
      u32 enc = (b & 0x80000000u) ? ~b : (b | 0x80000000u);
      atomicMax((u32*)&scal[0], enc);
    }
  }
}

// ---------------- mega2: upper-tri = Gram stats pass2 (needs vmax) | lower-tri = CE finalize ----------------
__launch_bounds__(256)
__global__ void mega2_k(const u16* __restrict__ mb, float* __restrict__ scal,
                        const float* __restrict__ rowse_s, const float* __restrict__ rowsum_s,
                        const float* __restrict__ rowtgt_s,
                        const float* __restrict__ rowse_c, const float* __restrict__ rowsum_c,
                        const float* __restrict__ rowtgt_c) {
  const int bx = blockIdx.x, by = blockIdx.y;
  const int tid = threadIdx.x;

  if (by > bx) {  // CE finalize on otherwise-idle lower-tri blocks
    const int lin = (by * (by - 1)) / 2 + bx;
    if (lin >= 56) return;
    const int idx = lin * 256 + tid;
    float ls = 0.f, lc = 0.f;
    if (idx < BATCH) {
      ls = 30.0f + logf(rowse_s[idx]) - 0.9f * rowtgt_s[idx] - (0.1f / (float)CCLS) * rowsum_s[idx];
    } else {
      const int j = idx - BATCH;
      if (j < CCLS)
        lc = 30.0f + logf(rowse_c[j]) - 0.9f * rowtgt_c[j] - (0.1f / (float)CCLS) * rowsum_c[j];
    }
    ls = wave_sum(ls);
    lc = wave_sum(lc);
    if ((tid & 63) == 0) {
      atomicAdd(&scal[3], ls);
      atomicAdd(&scal[4], lc);
    }
    return;
  }

  __shared__ u16 As[2][8192];
  __shared__ u16 Bs[2][8192];
  float* red = (float*)As;

  const int lane = tid & 63;
  const int wid = tid >> 6;
  const int row0 = by * 128;
  const int col0 = bx * 128;
  const int wm = wid >> 1, wn = wid & 1;

  u32 u = __float_as_uint(scal[0]);
  u32 bits = (u & 0x80000000u) ? (u ^ 0x80000000u) : ~u;
  const float vmax = __uint_as_float(bits);
  const float aco = -(2.0f - vmax) / vmax;                 // arg = cco + aco*g
  const float cco = (2.0f - vmax) - shift_of(vmax);

  f32x4 acc[4][4];
#pragma unroll
  for (int i = 0; i < 4; ++i)
#pragma unroll
    for (int j = 0; j < 4; ++j)
      acc[i][j] = (f32x4){0.f, 0.f, 0.f, 0.f};

  gemm_core(mb, mb, row0, col0, wid, lane, As, Bs, acc);

  const int rl = (lane >> 4) * 4;
  const int cl = lane & 15;
  float lsum = 0.f;
#pragma unroll
  for (int mi = 0; mi < 4; ++mi)
#pragma unroll
    for (int r = 0; r < 4; ++r) {
      const int gi = row0 + wm * 64 + mi * 16 + rl + r;
#pragma unroll
      for (int ni = 0; ni < 4; ++ni) {
        const int gj = col0 + wn * 64 + ni * 16 + cl;
        if (gi < CCLS && gj < CCLS && gi != gj) {
          float g = 2.0f * acc[mi][ni][r];
          lsum += __expf(fmaf(aco, g, cco));
        }
      }
    }
  const float wgt = (bx == by) ? 1.0f : 2.0f;
  lsum = wave_sum(lsum) * wgt;
  __syncthreads();
  if (lane == 0) red[wid] = lsum;
  __syncthreads();
  if (tid == 0) atomicAdd(&scal[2], red[0] + red[1] + red[2] + red[3]);
}

// ---------------- finalize loss ----------------
__global__ void finalize_k(const float* __restrict__ scal, float* __restrict__ out) {
  u32 u = __float_as_uint(scal[0]);
  u32 bits = (u & 0x80000000u) ? (u ^ 0x80000000u) : ~u;
  float vmax = __uint_as_float(bits);
  float s1 = scal[1], s2 = scal[2], ces = scal[3], cec = scal[4];
  float lse1 = 2.0f + logf(s1);
  float lse2 = shift_of(vmax) + logf(s2);
  float z = lse1 - lse2 + vmax;
  float sp = (z > 20.f) ? z : log1pf(expf(z));
  out[0] = sp + 0.5f * (cec / (float)CCLS) + 0.5f * (ces / (float)BATCH);
}

extern "C" void kernel_launch(void* const* d_in, const int* in_sizes, int n_in,
                              void* d_out, int out_size, void* d_ws, size_t ws_size,
                              hipStream_t stream) {
  (void)in_sizes; (void)n_in; (void)out_size; (void)ws_size;
  const float* x = (const float*)d_in[0];
  const float* w = (const float*)d_in[1];
  const int* label = (const int*)d_in[2];
  float* out = (float*)d_out;
  float* out1 = out + 1;                                  // output_sample [B, C]
  float* out2 = out + 1 + (size_t)BATCH * CCLS;           // output_center[label] [B, C]

  char* ws = (char*)d_ws;
  size_t o = 0;
  u16* xb = (u16*)(ws + o); o += (size_t)BATCH * KDIM * 2;
  u16* wb = (u16*)(ws + o); o += (size_t)CPAD * KDIM * 2;
  u16* mb = (u16*)(ws + o); o += (size_t)CPAD * KDIM * 2;
  const size_t zo = o;                                    // ---- zeroed region ----
  float* sumx = (float*)(ws + o); o += (size_t)CCLS * KDIM * 4;
  float* cnts = (float*)(ws + o); o += (size_t)CPAD * 4;
  float* scal = (float*)(ws + o); o += 256;
  float* rowse_s = (float*)(ws + o); o += (size_t)BATCH * 4;
  float* rowsum_s = (float*)(ws + o); o += (size_t)BATCH * 4;
  float* rowse_c = (float*)(ws + o); o += (size_t)CPAD * 4;
  float* rowsum_c = (float*)(ws + o); o += (size_t)CPAD * 4;
  int* ecnt = (int*)(ws + o); o += (size_t)CPAD * 4;
  const size_t ze = o;                                    // ---- end zeroed ----
  float* rowtgt_s = (float*)(ws + o); o += (size_t)BATCH * 4;   // fully written before read
  float* rowtgt_c = (float*)(ws + o); o += (size_t)CPAD * 4;
  int* eidx = (int*)(ws + o); o += (size_t)CCLS * EMAX * 4;

  const int n4 = (int)((ze - zo) / 16);
  zero_k<<<(n4 + 255) / 256, 256, 0, stream>>>((f32x4*)(ws + zo), n4);

  prep_k<<<CPAD / 4 + BATCH / 4, 256, 0, stream>>>(x, w, label, xb, wb, sumx, cnts, ecnt, eidx);
  mean_k<<<CPAD / 4, 256, 0, stream>>>(sumx, cnts, mb);

  mega1_k<<<dim3(47, 64, 3), 256, 0, stream>>>(xb, wb, mb, label, out1, out2, scal,
                                               rowse_s, rowsum_s, rowtgt_s,
                                               rowse_c, rowsum_c, rowtgt_c, ecnt, eidx);

  mega2_k<<<dim3(47, 47), 256, 0, stream>>>(mb, scal, rowse_s, rowsum_s, rowtgt_s,
                                            rowse_c, rowsum_c, rowtgt_c);

  finalize_k<<<1, 1, 0, stream>>>(scal, out);
}

// Round 4
// 405.207 us; speedup vs baseline: 1.0653x; 1.0653x over previous
//
#include <hip/hip_runtime.h>
#include <cstdint>
#include <cstddef>

#define CCLS 5994
#define CPAD 6016
#define BATCH 8192
#define KDIM 192
#define EMAX 24

#define S_SC 30.0f
#define COSM 0.9800665778412416f
#define SINM 0.19866933079506122f
#define THC  0.9800665778412416f
#define MMC  0.039733866159012244f

typedef __attribute__((ext_vector_type(8))) short short8;
typedef __attribute__((ext_vector_type(4))) float f32x4;
typedef unsigned short u16;
typedef unsigned int u32;

__device__ __forceinline__ u16 f2bf(float f) {
  u32 u = __float_as_uint(f);
  u32 r = (u + 0x7FFFu + ((u >> 16) & 1u)) >> 16;
  return (u16)r;
}

__device__ __forceinline__ float arc_phi(float c) {
  float s2 = fminf(fmaxf(1.0f - c * c, 0.0f), 1.0f);
  float sine = sqrtf(s2);
  return (c - THC > 0.0f) ? (c - MMC) : (c * COSM - sine * SINM);
}

__device__ __forceinline__ float shift_of(float vmax) {
  return (2.0f - vmax) * (1.0f + 2.0f / vmax);
}

__device__ __forceinline__ float wave_sum(float v) {
#pragma unroll
  for (int off = 1; off < 64; off <<= 1) v += __shfl_xor(v, off);
  return v;
}

// ---------------- fast zero (hipMemsetAsync fill path measured 237us @ 20GB/s; this is ~2us) ----------------
__global__ void zero_k(f32x4* __restrict__ p, int n4) {
  const int i = blockIdx.x * 256 + threadIdx.x;
  if (i < n4) p[i] = (f32x4){0.f, 0.f, 0.f, 0.f};
}

// ---------------- fused: normalize w -> wb | normalize x -> xb + segment sums + inverse lists ----------------
__global__ void prep_k(const float* __restrict__ x, const float* __restrict__ w,
                       const int* __restrict__ label,
                       u16* __restrict__ xb, u16* __restrict__ wb,
                       float* __restrict__ sumx, float* __restrict__ cnts,
                       int* __restrict__ ecnt, int* __restrict__ eidx) {
  const int bid = blockIdx.x;
  const int lane = threadIdx.x & 63;
  const int sub = threadIdx.x >> 6;
  if (bid < CPAD / 4) {
    const int row = bid * 4 + sub;
    float v0 = 0.f, v1 = 0.f, v2 = 0.f;
    if (row < CCLS) {
      const float* p = w + (size_t)row * KDIM;
      v0 = p[lane]; v1 = p[lane + 64]; v2 = p[lane + 128];
    }
    float ss = wave_sum(v0 * v0 + v1 * v1 + v2 * v2);
    float inv = 1.0f / fmaxf(sqrtf(ss), 1e-12f);
    if (row >= CCLS) inv = 0.f;
    u16* q = wb + (size_t)row * KDIM;
    q[lane] = f2bf(v0 * inv);
    q[lane + 64] = f2bf(v1 * inv);
    q[lane + 128] = f2bf(v2 * inv);
  } else {
    const int row = (bid - CPAD / 4) * 4 + sub;
    const float* p = x + (size_t)row * KDIM;
    float v0 = p[lane], v1 = p[lane + 64], v2 = p[lane + 128];
    float ss = wave_sum(v0 * v0 + v1 * v1 + v2 * v2);
    float inv = 1.0f / fmaxf(sqrtf(ss), 1e-12f);
    float n0 = v0 * inv, n1 = v1 * inv, n2 = v2 * inv;
    u16* q = xb + (size_t)row * KDIM;
    q[lane] = f2bf(n0); q[lane + 64] = f2bf(n1); q[lane + 128] = f2bf(n2);
    const int lab = label[row];
    float* sp = sumx + (size_t)lab * KDIM;
    atomicAdd(&sp[lane], n0);
    atomicAdd(&sp[lane + 64], n1);
    atomicAdd(&sp[lane + 128], n2);
    if (lane == 0) {
      atomicAdd(&cnts[lab], 1.0f);
      if (row >= CCLS) {
        int pos = atomicAdd(&ecnt[lab], 1);
        if (pos < EMAX) eidx[lab * EMAX + pos] = row;
      }
    }
  }
}

// ---------------- class means -> bf16 (padded rows zeroed) ----------------
__global__ void mean_k(const float* __restrict__ sumx, const float* __restrict__ cnts,
                       u16* __restrict__ mb) {
  const int row = blockIdx.x * 4 + (threadIdx.x >> 6);
  const int lane = threadIdx.x & 63;
  u16* q = mb + (size_t)row * KDIM;
  if (row < CCLS) {
    const float inv = 1.0f / cnts[row];
    const float* sp = sumx + (size_t)row * KDIM;
    q[lane] = f2bf(sp[lane] * inv);
    q[lane + 64] = f2bf(sp[lane + 64] * inv);
    q[lane + 128] = f2bf(sp[lane + 128] * inv);
  } else {
    q[lane] = 0; q[lane + 64] = 0; q[lane + 128] = 0;
  }
}

// ---------------- GEMM: C = A(row-major [M,192]) * B(row-major [N,192])^T ----------------
// Single-buffer 32KB LDS -> 5 blocks/CU (R3's 64KB dbuf dropped occupancy to 2/CU, -3x perf).
// MODE 0: ArcFace sample epilogue -> out + fused CE row stats
// MODE 1: ArcFace center epilogue -> out rows < CCLS (+ dup rows for b>=CCLS) + fused CE row stats
// MODE 2: Gram stats pass1 (upper-tri): encoded vmax -> scal[0], sum exp(G-2) -> scal[1]
// MODE 3: Gram stats pass2 (upper-tri): sum exp(cco + aco*G) -> scal[2]
template <int MODE>
__launch_bounds__(256)
__global__ void gemm_k(const u16* __restrict__ A, const u16* __restrict__ Bm,
                       float* __restrict__ out, const int* __restrict__ label,
                       float* __restrict__ scal,
                       float* __restrict__ rowse, float* __restrict__ rowsum,
                       float* __restrict__ rowtgt,
                       const int* __restrict__ ecnt, const int* __restrict__ eidx) {
  if (MODE >= 2 && blockIdx.y > blockIdx.x) return;  // symmetric Gram: upper-tri blocks only

  __shared__ u16 As[128 * 64];
  __shared__ u16 Bs[128 * 64];
  __shared__ float red[8];

  const int tid = threadIdx.x;
  const int lane = tid & 63;
  const int wid = tid >> 6;
  const int row0 = blockIdx.y * 128;
  const int col0 = blockIdx.x * 128;
  const int wm = wid >> 1;
  const int wn = wid & 1;

  float aco = 0.f, cco = 0.f;  // MODE 3: arg = cco + aco * g
  if (MODE == 3) {
    u32 u = __float_as_uint(scal[0]);
    u32 bits = (u & 0x80000000u) ? (u ^ 0x80000000u) : ~u;
    float vmax = __uint_as_float(bits);
    aco = -(2.0f - vmax) / vmax;
    cco = (2.0f - vmax) - shift_of(vmax);
  }

  f32x4 acc[4][4];
#pragma unroll
  for (int i = 0; i < 4; ++i)
#pragma unroll
    for (int j = 0; j < 4; ++j)
      acc[i][j] = (f32x4){0.f, 0.f, 0.f, 0.f};

  for (int k0 = 0; k0 < KDIM; k0 += 64) {
#pragma unroll
    for (int i = 0; i < 4; ++i) {
      const int c = wid * 4 + i;              // chunk 0..15, 1024B each
      const int r = c * 8 + (lane >> 3);      // tile row 0..127
      const int cc = (lane & 7) * 8;          // tile col (bf16)
      const u16* ga = A + (size_t)(row0 + r) * KDIM + (k0 + cc);
      const u16* gb = Bm + (size_t)(col0 + r) * KDIM + (k0 + cc);
      __builtin_amdgcn_global_load_lds((const __attribute__((address_space(1))) void*)ga,
                                       (__attribute__((address_space(3))) void*)(&As[c * 512]),
                                       16, 0, 0);
      __builtin_amdgcn_global_load_lds((const __attribute__((address_space(1))) void*)gb,
                                       (__attribute__((address_space(3))) void*)(&Bs[c * 512]),
                                       16, 0, 0);
    }
    asm volatile("s_waitcnt vmcnt(0)" ::: "memory");
    __syncthreads();
#pragma unroll
    for (int kk = 0; kk < 2; ++kk) {
      short8 af[4], bf[4];
#pragma unroll
      for (int mi = 0; mi < 4; ++mi)
        af[mi] = *(const short8*)&As[(wm * 64 + mi * 16 + (lane & 15)) * 64 + kk * 32 + (lane >> 4) * 8];
#pragma unroll
      for (int ni = 0; ni < 4; ++ni)
        bf[ni] = *(const short8*)&Bs[(wn * 64 + ni * 16 + (lane & 15)) * 64 + kk * 32 + (lane >> 4) * 8];
#pragma unroll
      for (int mi = 0; mi < 4; ++mi)
#pragma unroll
        for (int ni = 0; ni < 4; ++ni)
          acc[mi][ni] = __builtin_amdgcn_mfma_f32_16x16x32_bf16(af[mi], bf[ni], acc[mi][ni], 0, 0, 0);
    }
    __syncthreads();
  }

  const int rl = (lane >> 4) * 4;  // C/D: row = (lane>>4)*4 + reg, col = lane&15
  const int cl = lane & 15;

  if (MODE == 0 || MODE == 1) {
#pragma unroll
    for (int mi = 0; mi < 4; ++mi) {
#pragma unroll
      for (int r = 0; r < 4; ++r) {
        const int gr = row0 + wm * 64 + mi * 16 + rl + r;  // uniform across the 16-lane group
        if (MODE == 1 && gr >= CCLS) continue;
        const int tgt = (MODE == 0) ? label[gr] : gr;
        int ec = 0;
        if (MODE == 1) ec = min(ecnt[gr], EMAX);
        float se = 0.f, sm = 0.f;
#pragma unroll
        for (int ni = 0; ni < 4; ++ni) {
          const int gc = col0 + wn * 64 + ni * 16 + cl;
          if (gc < CCLS) {
            float v = acc[mi][ni][r];
            float val = ((gc == tgt) ? arc_phi(v) : v) * S_SC;
            out[(size_t)gr * CCLS + gc] = val;
            if (MODE == 1)
              for (int k = 0; k < ec; ++k)
                out[(size_t)eidx[gr * EMAX + k] * CCLS + gc] = val;  // dup rows b>=CCLS
            se += __expf(val - 30.0f);
            sm += val;
            if (gc == tgt) rowtgt[gr] = val;  // unique writer
          }
        }
        // reduce across the 16-lane group sharing this row
#pragma unroll
        for (int m = 1; m < 16; m <<= 1) {
          se += __shfl_xor(se, m);
          sm += __shfl_xor(sm, m);
        }
        if (cl == 0) {
          atomicAdd(&rowse[gr], se);
          atomicAdd(&rowsum[gr], sm);
        }
      }
    }
  } else {
    float lsum = 0.f;
    float lmax = -3.0e38f;
#pragma unroll
    for (int mi = 0; mi < 4; ++mi)
#pragma unroll
      for (int r = 0; r < 4; ++r) {
        const int gi = row0 + wm * 64 + mi * 16 + rl + r;
#pragma unroll
        for (int ni = 0; ni < 4; ++ni) {
          const int gj = col0 + wn * 64 + ni * 16 + cl;
          if (gi < CCLS && gj < CCLS && gi != gj) {
            float g = 2.0f * acc[mi][ni][r];
            if (MODE == 2) {
              lsum += __expf(g - 2.0f);
              lmax = fmaxf(lmax, g);
            } else {
              lsum += __expf(fmaf(aco, g, cco));
            }
          }
        }
      }
    const float wgt = (blockIdx.x == blockIdx.y) ? 1.0f : 2.0f;  // off-diag blocks counted twice
    lsum = wave_sum(lsum) * wgt;
    if (MODE == 2) {
#pragma unroll
      for (int off = 1; off < 64; off <<= 1) lmax = fmaxf(lmax, __shfl_xor(lmax, off));
    }
    if (lane == 0) { red[wid] = lsum; red[4 + wid] = lmax; }
    __syncthreads();
    if (tid == 0) {
      float s = red[0] + red[1] + red[2] + red[3];
      atomicAdd(&scal[(MODE == 2) ? 1 : 2], s);
      if (MODE == 2) {
        float m = fmaxf(fmaxf(red[4], red[5]), fmaxf(red[6], red[7]));
        u32 b = __float_as_uint(m);
        u32 enc = (b & 0x80000000u) ? ~b : (b | 0x80000000u);
        atomicMax((u32*)&scal[0], enc);
      }
    }
  }
}

// ---------------- finalize CE from fused row stats ----------------
__global__ void ce_fin_k(const float* __restrict__ rowse_s, const float* __restrict__ rowsum_s,
                         const float* __restrict__ rowtgt_s, const float* __restrict__ rowse_c,
                         const float* __restrict__ rowsum_c, const float* __restrict__ rowtgt_c,
                         float* __restrict__ scal) {
  const int i = blockIdx.x * 256 + threadIdx.x;
  float ls = 0.f, lc = 0.f;
  if (i < BATCH) {
    float lse = 30.0f + logf(rowse_s[i]);
    ls = lse - 0.9f * rowtgt_s[i] - (0.1f / (float)CCLS) * rowsum_s[i];
  }
  if (i < CCLS) {
    float lse = 30.0f + logf(rowse_c[i]);
    lc = lse - 0.9f * rowtgt_c[i] - (0.1f / (float)CCLS) * rowsum_c[i];
  }
  ls = wave_sum(ls);
  lc = wave_sum(lc);
  if ((threadIdx.x & 63) == 0) {
    atomicAdd(&scal[3], ls);
    atomicAdd(&scal[4], lc);
  }
}

// ---------------- finalize loss ----------------
__global__ void finalize_k(const float* __restrict__ scal, float* __restrict__ out) {
  u32 u = __float_as_uint(scal[0]);
  u32 bits = (u & 0x80000000u) ? (u ^ 0x80000000u) : ~u;
  float vmax = __uint_as_float(bits);
  float s1 = scal[1], s2 = scal[2], ces = scal[3], cec = scal[4];
  float lse1 = 2.0f + logf(s1);
  float lse2 = shift_of(vmax) + logf(s2);
  float z = lse1 - lse2 + vmax;
  float sp = (z > 20.f) ? z : log1pf(expf(z));
  out[0] = sp + 0.5f * (cec / (float)CCLS) + 0.5f * (ces / (float)BATCH);
}

extern "C" void kernel_launch(void* const* d_in, const int* in_sizes, int n_in,
                              void* d_out, int out_size, void* d_ws, size_t ws_size,
                              hipStream_t stream) {
  (void)in_sizes; (void)n_in; (void)out_size; (void)ws_size;
  const float* x = (const float*)d_in[0];
  const float* w = (const float*)d_in[1];
  const int* label = (const int*)d_in[2];
  float* out = (float*)d_out;
  float* out1 = out + 1;                                  // output_sample [B, C]
  float* out2 = out + 1 + (size_t)BATCH * CCLS;           // output_center[label] [B, C]

  char* ws = (char*)d_ws;
  size_t o = 0;
  u16* xb = (u16*)(ws + o); o += (size_t)BATCH * KDIM * 2;
  u16* wb = (u16*)(ws + o); o += (size_t)CPAD * KDIM * 2;
  u16* mb = (u16*)(ws + o); o += (size_t)CPAD * KDIM * 2;
  const size_t zo = o;                                    // ---- zeroed region ----
  float* sumx = (float*)(ws + o); o += (size_t)CCLS * KDIM * 4;
  float* cnts = (float*)(ws + o); o += (size_t)CPAD * 4;
  float* scal = (float*)(ws + o); o += 256;
  float* rowse_s = (float*)(ws + o); o += (size_t)BATCH * 4;
  float* rowsum_s = (float*)(ws + o); o += (size_t)BATCH * 4;
  float* rowse_c = (float*)(ws + o); o += (size_t)CPAD * 4;
  float* rowsum_c = (float*)(ws + o); o += (size_t)CPAD * 4;
  int* ecnt = (int*)(ws + o); o += (size_t)CPAD * 4;
  const size_t ze = o;                                    // ---- end zeroed ----
  float* rowtgt_s = (float*)(ws + o); o += (size_t)BATCH * 4;   // fully written before read
  float* rowtgt_c = (float*)(ws + o); o += (size_t)CPAD * 4;
  int* eidx = (int*)(ws + o); o += (size_t)CCLS * EMAX * 4;

  const int n4 = (int)((ze - zo) / 16);
  zero_k<<<(n4 + 255) / 256, 256, 0, stream>>>((f32x4*)(ws + zo), n4);

  prep_k<<<CPAD / 4 + BATCH / 4, 256, 0, stream>>>(x, w, label, xb, wb, sumx, cnts, ecnt, eidx);
  mean_k<<<CPAD / 4, 256, 0, stream>>>(sumx, cnts, mb);

  gemm_k<0><<<dim3(47, 64), 256, 0, stream>>>(xb, wb, out1, label, scal,
                                              rowse_s, rowsum_s, rowtgt_s, nullptr, nullptr);
  gemm_k<1><<<dim3(47, 47), 256, 0, stream>>>(mb, wb, out2, label, scal,
                                              rowse_c, rowsum_c, rowtgt_c, ecnt, eidx);

  ce_fin_k<<<BATCH / 256, 256, 0, stream>>>(rowse_s, rowsum_s, rowtgt_s, rowse_c, rowsum_c, rowtgt_c, scal);

  gemm_k<2><<<dim3(47, 47), 256, 0, stream>>>(mb, mb, nullptr, nullptr, scal,
                                              nullptr, nullptr, nullptr, nullptr, nullptr);
  gemm_k<3><<<dim3(47, 47), 256, 0, stream>>>(mb, mb, nullptr, nullptr, scal,
                                              nullptr, nullptr, nullptr, nullptr, nullptr);

  finalize_k<<<1, 1, 0, stream>>>(scal, out);
}

// Round 5
// 359.126 us; speedup vs baseline: 1.2020x; 1.1283x over previous
//
#include <hip/hip_runtime.h>
#include <cstdint>
#include <cstddef>

#define CCLS 5994
#define CPAD 6016
#define BATCH 8192
#define KDIM 192

#define S_SC 30.0f
#define COSM 0.9800665778412416f
#define SINM 0.19866933079506122f
#define THC  0.9800665778412416f
#define MMC  0.039733866159012244f

typedef __attribute__((ext_vector_type(8))) short short8;
typedef __attribute__((ext_vector_type(4))) float f32x4;
typedef unsigned short u16;
typedef unsigned int u32;

__device__ __forceinline__ u16 f2bf(float f) {
  u32 u = __float_as_uint(f);
  u32 r = (u + 0x7FFFu + ((u >> 16) & 1u)) >> 16;
  return (u16)r;
}

__device__ __forceinline__ float arc_phi(float c) {
  float s2 = fminf(fmaxf(1.0f - c * c, 0.0f), 1.0f);
  float sine = sqrtf(s2);
  return (c - THC > 0.0f) ? (c - MMC) : (c * COSM - sine * SINM);
}

__device__ __forceinline__ float shift_of(float vmax) {
  return (2.0f - vmax) * (1.0f + 2.0f / vmax);
}

__device__ __forceinline__ float wave_sum(float v) {
#pragma unroll
  for (int off = 1; off < 64; off <<= 1) v += __shfl_xor(v, off);
  return v;
}

// ---------------- fast zero (hipMemsetAsync fill path measured 237us @ 20GB/s for 4.7MB; this is ~2us) ----------------
__global__ void zero_k(f32x4* __restrict__ p, int n4) {
  const int i = blockIdx.x * 256 + threadIdx.x;
  if (i < n4) p[i] = (f32x4){0.f, 0.f, 0.f, 0.f};
}

// ---------------- normalize weight -> bf16 (padded rows zeroed) ----------------
__global__ void norm_w_k(const float* __restrict__ w, u16* __restrict__ wb) {
  const int row = blockIdx.x * 4 + (threadIdx.x >> 6);
  const int lane = threadIdx.x & 63;
  float v0 = 0.f, v1 = 0.f, v2 = 0.f;
  if (row < CCLS) {
    const float* p = w + (size_t)row * KDIM;
    v0 = p[lane]; v1 = p[lane + 64]; v2 = p[lane + 128];
  }
  float ss = wave_sum(v0 * v0 + v1 * v1 + v2 * v2);
  float inv = 1.0f / fmaxf(sqrtf(ss), 1e-12f);
  if (row >= CCLS) inv = 0.f;
  u16* q = wb + (size_t)row * KDIM;
  q[lane] = f2bf(v0 * inv);
  q[lane + 64] = f2bf(v1 * inv);
  q[lane + 128] = f2bf(v2 * inv);
}

// ---------------- normalize x -> bf16, segment-sum into sumx/counts ----------------
__global__ void norm_x_k(const float* __restrict__ x, const int* __restrict__ label,
                         u16* __restrict__ xb, float* __restrict__ sumx, float* __restrict__ cnts) {
  const int row = blockIdx.x * 4 + (threadIdx.x >> 6);
  const int lane = threadIdx.x & 63;
  const float* p = x + (size_t)row * KDIM;
  float v0 = p[lane], v1 = p[lane + 64], v2 = p[lane + 128];
  float ss = wave_sum(v0 * v0 + v1 * v1 + v2 * v2);
  float inv = 1.0f / fmaxf(sqrtf(ss), 1e-12f);
  float n0 = v0 * inv, n1 = v1 * inv, n2 = v2 * inv;
  u16* q = xb + (size_t)row * KDIM;
  q[lane] = f2bf(n0); q[lane + 64] = f2bf(n1); q[lane + 128] = f2bf(n2);
  const int lab = label[row];
  float* sp = sumx + (size_t)lab * KDIM;
  atomicAdd(&sp[lane], n0);
  atomicAdd(&sp[lane + 64], n1);
  atomicAdd(&sp[lane + 128], n2);
  if (lane == 0) atomicAdd(&cnts[lab], 1.0f);
}

// ---------------- class means -> bf16 (padded rows zeroed) ----------------
__global__ void mean_k(const float* __restrict__ sumx, const float* __restrict__ cnts,
                       u16* __restrict__ mb) {
  const int row = blockIdx.x * 4 + (threadIdx.x >> 6);
  const int lane = threadIdx.x & 63;
  u16* q = mb + (size_t)row * KDIM;
  if (row < CCLS) {
    const float inv = 1.0f / cnts[row];
    const float* sp = sumx + (size_t)row * KDIM;
    q[lane] = f2bf(sp[lane] * inv);
    q[lane + 64] = f2bf(sp[lane + 64] * inv);
    q[lane + 128] = f2bf(sp[lane + 128] * inv);
  } else {
    q[lane] = 0; q[lane + 64] = 0; q[lane + 128] = 0;
  }
}

// ---------------- GEMM: C = A(row-major [M,192]) * B(row-major [N,192])^T ----------------
// Single-buffer 32KB LDS -> ~5 blocks/CU. (R3: 64KB dbuf -> 2 blocks/CU, 3x regression.)
// MODE 0: ArcFace sample epilogue -> out + fused CE row stats
// MODE 1: ArcFace center epilogue -> out rows < CCLS + fused CE row stats
// MODE 2: Gram stats pass1 (upper-tri): encoded vmax -> scal[0], sum exp(G-2) -> scal[1]
// MODE 3: Gram stats pass2 (upper-tri): sum exp(cco + aco*G) -> scal[2]
template <int MODE>
__launch_bounds__(256)
__global__ void gemm_k(const u16* __restrict__ A, const u16* __restrict__ Bm,
                       float* __restrict__ out, const int* __restrict__ label,
                       float* __restrict__ scal,
                       float* __restrict__ rowse, float* __restrict__ rowsum,
                       float* __restrict__ rowtgt) {
  if (MODE >= 2 && blockIdx.y > blockIdx.x) return;  // symmetric Gram: upper-tri blocks only

  __shared__ u16 As[128 * 64];
  __shared__ u16 Bs[128 * 64];
  __shared__ float red[8];

  const int tid = threadIdx.x;
  const int lane = tid & 63;
  const int wid = tid >> 6;
  const int row0 = blockIdx.y * 128;
  const int col0 = blockIdx.x * 128;
  const int wm = wid >> 1;
  const int wn = wid & 1;

  float aco = 0.f, cco = 0.f;  // MODE 3: arg = cco + aco * g
  if (MODE == 3) {
    u32 u = __float_as_uint(scal[0]);
    u32 bits = (u & 0x80000000u) ? (u ^ 0x80000000u) : ~u;
    float vmax = __uint_as_float(bits);
    aco = -(2.0f - vmax) / vmax;
    cco = (2.0f - vmax) - shift_of(vmax);
  }

  f32x4 acc[4][4];
#pragma unroll
  for (int i = 0; i < 4; ++i)
#pragma unroll
    for (int j = 0; j < 4; ++j)
      acc[i][j] = (f32x4){0.f, 0.f, 0.f, 0.f};

  for (int k0 = 0; k0 < KDIM; k0 += 64) {
#pragma unroll
    for (int i = 0; i < 4; ++i) {
      const int c = wid * 4 + i;              // chunk 0..15, 1024B each
      const int r = c * 8 + (lane >> 3);      // tile row 0..127
      const int cc = (lane & 7) * 8;          // tile col (bf16)
      const u16* ga = A + (size_t)(row0 + r) * KDIM + (k0 + cc);
      const u16* gb = Bm + (size_t)(col0 + r) * KDIM + (k0 + cc);
      __builtin_amdgcn_global_load_lds((const __attribute__((address_space(1))) void*)ga,
                                       (__attribute__((address_space(3))) void*)(&As[c * 512]),
                                       16, 0, 0);
      __builtin_amdgcn_global_load_lds((const __attribute__((address_space(1))) void*)gb,
                                       (__attribute__((address_space(3))) void*)(&Bs[c * 512]),
                                       16, 0, 0);
    }
    asm volatile("s_waitcnt vmcnt(0)" ::: "memory");
    __syncthreads();
#pragma unroll
    for (int kk = 0; kk < 2; ++kk) {
      short8 af[4], bf[4];
#pragma unroll
      for (int mi = 0; mi < 4; ++mi)
        af[mi] = *(const short8*)&As[(wm * 64 + mi * 16 + (lane & 15)) * 64 + kk * 32 + (lane >> 4) * 8];
#pragma unroll
      for (int ni = 0; ni < 4; ++ni)
        bf[ni] = *(const short8*)&Bs[(wn * 64 + ni * 16 + (lane & 15)) * 64 + kk * 32 + (lane >> 4) * 8];
#pragma unroll
      for (int mi = 0; mi < 4; ++mi)
#pragma unroll
        for (int ni = 0; ni < 4; ++ni)
          acc[mi][ni] = __builtin_amdgcn_mfma_f32_16x16x32_bf16(af[mi], bf[ni], acc[mi][ni], 0, 0, 0);
    }
    __syncthreads();
  }

  const int rl = (lane >> 4) * 4;  // C/D: row = (lane>>4)*4 + reg, col = lane&15
  const int cl = lane & 15;

  if (MODE == 0 || MODE == 1) {
#pragma unroll
    for (int mi = 0; mi < 4; ++mi) {
#pragma unroll
      for (int r = 0; r < 4; ++r) {
        const int gr = row0 + wm * 64 + mi * 16 + rl + r;  // uniform across the 16-lane group
        if (MODE == 1 && gr >= CCLS) continue;
        const int tgt = (MODE == 0) ? label[gr] : gr;
        float se = 0.f, sm = 0.f;
#pragma unroll
        for (int ni = 0; ni < 4; ++ni) {
          const int gc = col0 + wn * 64 + ni * 16 + cl;
          if (gc < CCLS) {
            float v = acc[mi][ni][r];
            float val = ((gc == tgt) ? arc_phi(v) : v) * S_SC;
            out[(size_t)gr * CCLS + gc] = val;
            se += __expf(val - 30.0f);
            sm += val;
            if (gc == tgt) rowtgt[gr] = val;  // unique writer
          }
        }
        // reduce across the 16-lane group sharing this row
#pragma unroll
        for (int m = 1; m < 16; m <<= 1) {
          se += __shfl_xor(se, m);
          sm += __shfl_xor(sm, m);
        }
        if (cl == 0) {
          atomicAdd(&rowse[gr], se);
          atomicAdd(&rowsum[gr], sm);
        }
      }
    }
  } else {
    float lsum = 0.f;
    float lmax = -3.0e38f;
#pragma unroll
    for (int mi = 0; mi < 4; ++mi)
#pragma unroll
      for (int r = 0; r < 4; ++r) {
        const int gi = row0 + wm * 64 + mi * 16 + rl + r;
#pragma unroll
        for (int ni = 0; ni < 4; ++ni) {
          const int gj = col0 + wn * 64 + ni * 16 + cl;
          if (gi < CCLS && gj < CCLS && gi != gj) {
            float g = 2.0f * acc[mi][ni][r];
            if (MODE == 2) {
              lsum += __expf(g - 2.0f);
              lmax = fmaxf(lmax, g);
            } else {
              lsum += __expf(fmaf(aco, g, cco));
            }
          }
        }
      }
    const float wgt = (blockIdx.x == blockIdx.y) ? 1.0f : 2.0f;  // off-diag blocks counted twice
    lsum = wave_sum(lsum) * wgt;
    if (MODE == 2) {
#pragma unroll
      for (int off = 1; off < 64; off <<= 1) lmax = fmaxf(lmax, __shfl_xor(lmax, off));
    }
    if (lane == 0) { red[wid] = lsum; red[4 + wid] = lmax; }
    __syncthreads();
    if (tid == 0) {
      float s = red[0] + red[1] + red[2] + red[3];
      atomicAdd(&scal[(MODE == 2) ? 1 : 2], s);
      if (MODE == 2) {
        float m = fmaxf(fmaxf(red[4], red[5]), fmaxf(red[6], red[7]));
        u32 b = __float_as_uint(m);
        u32 enc = (b & 0x80000000u) ? ~b : (b | 0x80000000u);
        atomicMax((u32*)&scal[0], enc);
      }
    }
  }
}

// ---------------- gather rows b >= CCLS: out2[b,:] = out2[label[b],:] ----------------
__global__ void gather_k(const int* __restrict__ label, float* __restrict__ out2) {
  const int b = CCLS + blockIdx.x;
  const int r = label[b];
  const float* src = out2 + (size_t)r * CCLS;
  float* dst = out2 + (size_t)b * CCLS;
  for (int j = threadIdx.x; j < CCLS; j += 256) dst[j] = src[j];
}

// ---------------- finalize CE from fused row stats ----------------
__global__ void ce_fin_k(const float* __restrict__ rowse_s, const float* __restrict__ rowsum_s,
                         const float* __restrict__ rowtgt_s, const float* __restrict__ rowse_c,
                         const float* __restrict__ rowsum_c, const float* __restrict__ rowtgt_c,
                         float* __restrict__ scal) {
  const int i = blockIdx.x * 256 + threadIdx.x;
  float ls = 0.f, lc = 0.f;
  if (i < BATCH) {
    float lse = 30.0f + logf(rowse_s[i]);
    ls = lse - 0.9f * rowtgt_s[i] - (0.1f / (float)CCLS) * rowsum_s[i];
  }
  if (i < CCLS) {
    float lse = 30.0f + logf(rowse_c[i]);
    lc = lse - 0.9f * rowtgt_c[i] - (0.1f / (float)CCLS) * rowsum_c[i];
  }
  ls = wave_sum(ls);
  lc = wave_sum(lc);
  if ((threadIdx.x & 63) == 0) {
    atomicAdd(&scal[3], ls);
    atomicAdd(&scal[4], lc);
  }
}

// ---------------- finalize loss ----------------
__global__ void finalize_k(const float* __restrict__ scal, float* __restrict__ out) {
  u32 u = __float_as_uint(scal[0]);
  u32 bits = (u & 0x80000000u) ? (u ^ 0x80000000u) : ~u;
  float vmax = __uint_as_float(bits);
  float s1 = scal[1], s2 = scal[2], ces = scal[3], cec = scal[4];
  float lse1 = 2.0f + logf(s1);
  float lse2 = shift_of(vmax) + logf(s2);
  float z = lse1 - lse2 + vmax;
  float sp = (z > 20.f) ? z : log1pf(expf(z));
  out[0] = sp + 0.5f * (cec / (float)CCLS) + 0.5f * (ces / (float)BATCH);
}

extern "C" void kernel_launch(void* const* d_in, const int* in_sizes, int n_in,
                              void* d_out, int out_size, void* d_ws, size_t ws_size,
                              hipStream_t stream) {
  (void)in_sizes; (void)n_in; (void)out_size; (void)ws_size;
  const float* x = (const float*)d_in[0];
  const float* w = (const float*)d_in[1];
  const int* label = (const int*)d_in[2];
  float* out = (float*)d_out;
  float* out1 = out + 1;                                  // output_sample [B, C]
  float* out2 = out + 1 + (size_t)BATCH * CCLS;           // output_center[label] [B, C]

  char* ws = (char*)d_ws;
  size_t o = 0;
  u16* xb = (u16*)(ws + o); o += (size_t)BATCH * KDIM * 2;   // x1 bf16
  u16* wb = (u16*)(ws + o); o += (size_t)CPAD * KDIM * 2;    // w bf16 (padded)
  u16* mb = (u16*)(ws + o); o += (size_t)CPAD * KDIM * 2;    // mean bf16 (padded)
  const size_t zo = o;                                       // ---- zeroed region ----
  float* sumx = (float*)(ws + o); o += (size_t)CCLS * KDIM * 4;
  float* cnts = (float*)(ws + o); o += (size_t)CPAD * 4;
  float* scal = (float*)(ws + o); o += 256;
  float* rowse_s = (float*)(ws + o); o += (size_t)BATCH * 4;
  float* rowsum_s = (float*)(ws + o); o += (size_t)BATCH * 4;
  float* rowse_c = (float*)(ws + o); o += (size_t)CPAD * 4;
  float* rowsum_c = (float*)(ws + o); o += (size_t)CPAD * 4;
  const size_t ze = o;                                       // ---- end zeroed ----
  float* rowtgt_s = (float*)(ws + o); o += (size_t)BATCH * 4;  // fully written before read
  float* rowtgt_c = (float*)(ws + o); o += (size_t)CPAD * 4;

  const int n4 = (int)((ze - zo) / 16);
  zero_k<<<(n4 + 255) / 256, 256, 0, stream>>>((f32x4*)(ws + zo), n4);

  norm_w_k<<<CPAD / 4, 256, 0, stream>>>(w, wb);
  norm_x_k<<<BATCH / 4, 256, 0, stream>>>(x, label, xb, sumx, cnts);
  mean_k<<<CPAD / 4, 256, 0, stream>>>(sumx, cnts, mb);

  gemm_k<0><<<dim3(47, 64), 256, 0, stream>>>(xb, wb, out1, label, scal, rowse_s, rowsum_s, rowtgt_s);
  gemm_k<1><<<dim3(47, 47), 256, 0, stream>>>(mb, wb, out2, label, scal, rowse_c, rowsum_c, rowtgt_c);
  gather_k<<<BATCH - CCLS, 256, 0, stream>>>(label, out2);

  ce_fin_k<<<BATCH / 256, 256, 0, stream>>>(rowse_s, rowsum_s, rowtgt_s, rowse_c, rowsum_c, rowtgt_c, scal);

  gemm_k<2><<<dim3(47, 47), 256, 0, stream>>>(mb, mb, nullptr, nullptr, scal, nullptr, nullptr, nullptr);
  gemm_k<3><<<dim3(47, 47), 256, 0, stream>>>(mb, mb, nullptr, nullptr, scal, nullptr, nullptr, nullptr);

  finalize_k<<<1, 1, 0, stream>>>(scal, out);
}

// Round 6
// 349.922 us; speedup vs baseline: 1.2336x; 1.0263x over previous
//
#include <hip/hip_runtime.h>
#include <cstdint>
#include <cstddef>

#define CCLS 5994
#define CPAD 6016
#define BATCH 8192
#define KDIM 192

#define S_SC 30.0f
#define COSM 0.9800665778412416f
#define SINM 0.19866933079506122f
#define THC  0.9800665778412416f
#define MMC  0.039733866159012244f

typedef __attribute__((ext_vector_type(8))) short short8;
typedef __attribute__((ext_vector_type(4))) float f32x4;
typedef unsigned short u16;
typedef unsigned int u32;

__device__ __forceinline__ u16 f2bf(float f) {
  u32 u = __float_as_uint(f);
  u32 r = (u + 0x7FFFu + ((u >> 16) & 1u)) >> 16;
  return (u16)r;
}

__device__ __forceinline__ float arc_phi(float c) {
  float s2 = fminf(fmaxf(1.0f - c * c, 0.0f), 1.0f);
  float sine = sqrtf(s2);
  return (c - THC > 0.0f) ? (c - MMC) : (c * COSM - sine * SINM);
}

__device__ __forceinline__ float shift_of(float vmax) {
  return (2.0f - vmax) * (1.0f + 2.0f / vmax);
}

__device__ __forceinline__ float wave_sum(float v) {
#pragma unroll
  for (int off = 1; off < 64; off <<= 1) v += __shfl_xor(v, off);
  return v;
}

// ---------------- fast zero ----------------
__global__ void zero_k(f32x4* __restrict__ p, int n4) {
  const int i = blockIdx.x * 256 + threadIdx.x;
  if (i < n4) p[i] = (f32x4){0.f, 0.f, 0.f, 0.f};
}

// ---------------- normalize weight -> bf16 (padded rows zeroed) ----------------
__global__ void norm_w_k(const float* __restrict__ w, u16* __restrict__ wb) {
  const int row = blockIdx.x * 4 + (threadIdx.x >> 6);
  const int lane = threadIdx.x & 63;
  float v0 = 0.f, v1 = 0.f, v2 = 0.f;
  if (row < CCLS) {
    const float* p = w + (size_t)row * KDIM;
    v0 = p[lane]; v1 = p[lane + 64]; v2 = p[lane + 128];
  }
  float ss = wave_sum(v0 * v0 + v1 * v1 + v2 * v2);
  float inv = 1.0f / fmaxf(sqrtf(ss), 1e-12f);
  if (row >= CCLS) inv = 0.f;
  u16* q = wb + (size_t)row * KDIM;
  q[lane] = f2bf(v0 * inv);
  q[lane + 64] = f2bf(v1 * inv);
  q[lane + 128] = f2bf(v2 * inv);
}

// ---------------- normalize x -> bf16, segment-sum into sumx/counts ----------------
__global__ void norm_x_k(const float* __restrict__ x, const int* __restrict__ label,
                         u16* __restrict__ xb, float* __restrict__ sumx, float* __restrict__ cnts) {
  const int row = blockIdx.x * 4 + (threadIdx.x >> 6);
  const int lane = threadIdx.x & 63;
  const float* p = x + (size_t)row * KDIM;
  float v0 = p[lane], v1 = p[lane + 64], v2 = p[lane + 128];
  float ss = wave_sum(v0 * v0 + v1 * v1 + v2 * v2);
  float inv = 1.0f / fmaxf(sqrtf(ss), 1e-12f);
  float n0 = v0 * inv, n1 = v1 * inv, n2 = v2 * inv;
  u16* q = xb + (size_t)row * KDIM;
  q[lane] = f2bf(n0); q[lane + 64] = f2bf(n1); q[lane + 128] = f2bf(n2);
  const int lab = label[row];
  float* sp = sumx + (size_t)lab * KDIM;
  atomicAdd(&sp[lane], n0);
  atomicAdd(&sp[lane + 64], n1);
  atomicAdd(&sp[lane + 128], n2);
  if (lane == 0) atomicAdd(&cnts[lab], 1.0f);
}

// ---------------- class means -> bf16 (padded rows zeroed) ----------------
__global__ void mean_k(const float* __restrict__ sumx, const float* __restrict__ cnts,
                       u16* __restrict__ mb) {
  const int row = blockIdx.x * 4 + (threadIdx.x >> 6);
  const int lane = threadIdx.x & 63;
  u16* q = mb + (size_t)row * KDIM;
  if (row < CCLS) {
    const float inv = 1.0f / cnts[row];
    const float* sp = sumx + (size_t)row * KDIM;
    q[lane] = f2bf(sp[lane] * inv);
    q[lane + 64] = f2bf(sp[lane + 64] * inv);
    q[lane + 128] = f2bf(sp[lane + 128] * inv);
  } else {
    q[lane] = 0; q[lane + 64] = 0; q[lane + 128] = 0;
  }
}

// ---- stage one 128x32 bf16 tile pair (A,B) into LDS via global_load_lds (linear dest) ----
// 8KB per matrix; per wave: 2 A-loads + 2 B-loads (16B/lane). Layout [128 rows][32 cols],
// 64B rows -> ds_read_b128 of a full row is bank-conflict-FREE (8 accesses/bank = minimum).
__device__ __forceinline__ void stage32(const u16* __restrict__ A, const u16* __restrict__ Bm,
                                        int row0, int col0, int wid, int lane, int k0,
                                        u16* As, u16* Bs) {
#pragma unroll
  for (int i = 0; i < 2; ++i) {
    const int c = wid * 2 + i;               // chunk 0..7, 16 rows each
    const int r = c * 16 + (lane >> 2);      // tile row 0..127
    const int cc = (lane & 3) * 8;           // tile col (bf16 units)
    const u16* ga = A + (size_t)(row0 + r) * KDIM + (k0 + cc);
    const u16* gb = Bm + (size_t)(col0 + r) * KDIM + (k0 + cc);
    __builtin_amdgcn_global_load_lds((const __attribute__((address_space(1))) void*)ga,
                                     (__attribute__((address_space(3))) void*)(As + c * 512),
                                     16, 0, 0);
    __builtin_amdgcn_global_load_lds((const __attribute__((address_space(1))) void*)gb,
                                     (__attribute__((address_space(3))) void*)(Bs + c * 512),
                                     16, 0, 0);
  }
}

// ---------------- GEMM: C = A(row-major [M,192]) * B(row-major [N,192])^T ----------------
// 32KB LDS exactly (red aliased) -> 5 blocks/CU. BK=32 double-buffer, counted vmcnt(4)
// (never 0 mid-loop), raw s_barrier (no implicit vmcnt drain), sched_barrier fences.
// MODE 0: ArcFace sample epilogue -> out + fused CE row stats
// MODE 1: ArcFace center epilogue -> out rows < CCLS + fused CE row stats
// MODE 2: Gram stats pass1 (upper-tri): encoded vmax -> scal[0], sum exp(G-2) -> scal[1]
// MODE 3: Gram stats pass2 (upper-tri): sum exp(cco + aco*G) -> scal[2]
template <int MODE>
__launch_bounds__(256)
__global__ void gemm_k(const u16* __restrict__ A, const u16* __restrict__ Bm,
                       float* __restrict__ out, const int* __restrict__ label,
                       float* __restrict__ scal,
                       float* __restrict__ rowse, float* __restrict__ rowsum,
                       float* __restrict__ rowtgt) {
  if (MODE >= 2 && blockIdx.y > blockIdx.x) return;  // symmetric Gram: upper-tri blocks only

  __shared__ u16 lds[2][2][4096];  // [buf][A/B][128x32 bf16] = 32768 B exactly
  float* red = (float*)&lds[0][0][0];  // aliased; used only after final barrier

  const int tid = threadIdx.x;
  const int lane = tid & 63;
  const int wid = tid >> 6;
  const int row0 = blockIdx.y * 128;
  const int col0 = blockIdx.x * 128;
  const int wm = wid >> 1;
  const int wn = wid & 1;

  float aco = 0.f, cco = 0.f;  // MODE 3: arg = cco + aco * g
  if (MODE == 3) {
    u32 u = __float_as_uint(scal[0]);
    u32 bits = (u & 0x80000000u) ? (u ^ 0x80000000u) : ~u;
    float vmax = __uint_as_float(bits);
    aco = -(2.0f - vmax) / vmax;
    cco = (2.0f - vmax) - shift_of(vmax);
  }

  f32x4 acc[4][4];
#pragma unroll
  for (int i = 0; i < 4; ++i)
#pragma unroll
    for (int j = 0; j < 4; ++j)
      acc[i][j] = (f32x4){0.f, 0.f, 0.f, 0.f};

  stage32(A, Bm, row0, col0, wid, lane, 0,  &lds[0][0][0], &lds[0][1][0]);
  stage32(A, Bm, row0, col0, wid, lane, 32, &lds[1][0][0], &lds[1][1][0]);

  // Per step: wait own 4 oldest loads -> barrier (all waves' chunks in) -> read+MFMA ->
  // barrier (all reads of this buf done) -> restage this buf for step T+2.
#define GSTEP(T, WN)                                                                         \
  {                                                                                          \
    asm volatile("s_waitcnt vmcnt(" #WN ")" ::: "memory");                                   \
    __builtin_amdgcn_s_barrier();                                                            \
    __builtin_amdgcn_sched_barrier(0);                                                       \
    const u16* Ab = &lds[(T) & 1][0][0];                                                     \
    const u16* Bb = &lds[(T) & 1][1][0];                                                     \
    short8 af[4], bf[4];                                                                     \
    _Pragma("unroll")                                                                        \
    for (int mi = 0; mi < 4; ++mi)                                                           \
      af[mi] = *(const short8*)&Ab[(wm * 64 + mi * 16 + (lane & 15)) * 32 + (lane >> 4) * 8]; \
    _Pragma("unroll")                                                                        \
    for (int ni = 0; ni < 4; ++ni)                                                           \
      bf[ni] = *(const short8*)&Bb[(wn * 64 + ni * 16 + (lane & 15)) * 32 + (lane >> 4) * 8]; \
    _Pragma("unroll")                                                                        \
    for (int mi = 0; mi < 4; ++mi)                                                           \
      _Pragma("unroll")                                                                      \
      for (int ni = 0; ni < 4; ++ni)                                                         \
        acc[mi][ni] = __builtin_amdgcn_mfma_f32_16x16x32_bf16(af[mi], bf[ni], acc[mi][ni], 0, 0, 0); \
    __builtin_amdgcn_sched_barrier(0);                                                       \
    __builtin_amdgcn_s_barrier();                                                            \
    __builtin_amdgcn_sched_barrier(0);                                                       \
    if ((T) < 4)                                                                             \
      stage32(A, Bm, row0, col0, wid, lane, ((T) + 2) * 32,                                  \
              &lds[(T) & 1][0][0], &lds[(T) & 1][1][0]);                                     \
  }

  GSTEP(0, 4) GSTEP(1, 4) GSTEP(2, 4) GSTEP(3, 4) GSTEP(4, 4) GSTEP(5, 0)
#undef GSTEP

  const int rl = (lane >> 4) * 4;  // C/D: row = (lane>>4)*4 + reg, col = lane&15
  const int cl = lane & 15;

  if (MODE == 0 || MODE == 1) {
#pragma unroll
    for (int mi = 0; mi < 4; ++mi) {
#pragma unroll
      for (int r = 0; r < 4; ++r) {
        const int gr = row0 + wm * 64 + mi * 16 + rl + r;  // uniform across the 16-lane group
        if (MODE == 1 && gr >= CCLS) continue;
        const int tgt = (MODE == 0) ? label[gr] : gr;
        float se = 0.f, sm = 0.f;
#pragma unroll
        for (int ni = 0; ni < 4; ++ni) {
          const int gc = col0 + wn * 64 + ni * 16 + cl;
          if (gc < CCLS) {
            float v = acc[mi][ni][r];
            float val = ((gc == tgt) ? arc_phi(v) : v) * S_SC;
            out[(size_t)gr * CCLS + gc] = val;
            se += __expf(val - 30.0f);
            sm += val;
            if (gc == tgt) rowtgt[gr] = val;  // unique writer
          }
        }
        // reduce across the 16-lane group sharing this row
#pragma unroll
        for (int m = 1; m < 16; m <<= 1) {
          se += __shfl_xor(se, m);
          sm += __shfl_xor(sm, m);
        }
        if (cl == 0) {
          atomicAdd(&rowse[gr], se);
          atomicAdd(&rowsum[gr], sm);
        }
      }
    }
  } else {
    float lsum = 0.f;
    float lmax = -3.0e38f;
#pragma unroll
    for (int mi = 0; mi < 4; ++mi)
#pragma unroll
      for (int r = 0; r < 4; ++r) {
        const int gi = row0 + wm * 64 + mi * 16 + rl + r;
#pragma unroll
        for (int ni = 0; ni < 4; ++ni) {
          const int gj = col0 + wn * 64 + ni * 16 + cl;
          if (gi < CCLS && gj < CCLS && gi != gj) {
            float g = 2.0f * acc[mi][ni][r];
            if (MODE == 2) {
              lsum += __expf(g - 2.0f);
              lmax = fmaxf(lmax, g);
            } else {
              lsum += __expf(fmaf(aco, g, cco));
            }
          }
        }
      }
    const float wgt = (blockIdx.x == blockIdx.y) ? 1.0f : 2.0f;  // off-diag counted twice
    lsum = wave_sum(lsum) * wgt;
    if (MODE == 2) {
#pragma unroll
      for (int off = 1; off < 64; off <<= 1) lmax = fmaxf(lmax, __shfl_xor(lmax, off));
    }
    __syncthreads();  // all LDS tile reads complete before aliased red[] writes
    if (lane == 0) { red[wid] = lsum; red[4 + wid] = lmax; }
    __syncthreads();
    if (tid == 0) {
      float s = red[0] + red[1] + red[2] + red[3];
      atomicAdd(&scal[(MODE == 2) ? 1 : 2], s);
      if (MODE == 2) {
        float m = fmaxf(fmaxf(red[4], red[5]), fmaxf(red[6], red[7]));
        u32 b = __float_as_uint(m);
        u32 enc = (b & 0x80000000u) ? ~b : (b | 0x80000000u);
        atomicMax((u32*)&scal[0], enc);
      }
    }
  }
}

// ---------------- gather rows b >= CCLS: out2[b,:] = out2[label[b],:] ----------------
__global__ void gather_k(const int* __restrict__ label, float* __restrict__ out2) {
  const int b = CCLS + blockIdx.x;
  const int r = label[b];
  const float* src = out2 + (size_t)r * CCLS;
  float* dst = out2 + (size_t)b * CCLS;
  for (int j = threadIdx.x; j < CCLS; j += 256) dst[j] = src[j];
}

// ---------------- finalize CE from fused row stats ----------------
__global__ void ce_fin_k(const float* __restrict__ rowse_s, const float* __restrict__ rowsum_s,
                         const float* __restrict__ rowtgt_s, const float* __restrict__ rowse_c,
                         const float* __restrict__ rowsum_c, const float* __restrict__ rowtgt_c,
                         float* __restrict__ scal) {
  const int i = blockIdx.x * 256 + threadIdx.x;
  float ls = 0.f, lc = 0.f;
  if (i < BATCH) {
    float lse = 30.0f + logf(rowse_s[i]);
    ls = lse - 0.9f * rowtgt_s[i] - (0.1f / (float)CCLS) * rowsum_s[i];
  }
  if (i < CCLS) {
    float lse = 30.0f + logf(rowse_c[i]);
    lc = lse - 0.9f * rowtgt_c[i] - (0.1f / (float)CCLS) * rowsum_c[i];
  }
  ls = wave_sum(ls);
  lc = wave_sum(lc);
  if ((threadIdx.x & 63) == 0) {
    atomicAdd(&scal[3], ls);
    atomicAdd(&scal[4], lc);
  }
}

// ---------------- finalize loss ----------------
__global__ void finalize_k(const float* __restrict__ scal, float* __restrict__ out) {
  u32 u = __float_as_uint(scal[0]);
  u32 bits = (u & 0x80000000u) ? (u ^ 0x80000000u) : ~u;
  float vmax = __uint_as_float(bits);
  float s1 = scal[1], s2 = scal[2], ces = scal[3], cec = scal[4];
  float lse1 = 2.0f + logf(s1);
  float lse2 = shift_of(vmax) + logf(s2);
  float z = lse1 - lse2 + vmax;
  float sp = (z > 20.f) ? z : log1pf(expf(z));
  out[0] = sp + 0.5f * (cec / (float)CCLS) + 0.5f * (ces / (float)BATCH);
}

extern "C" void kernel_launch(void* const* d_in, const int* in_sizes, int n_in,
                              void* d_out, int out_size, void* d_ws, size_t ws_size,
                              hipStream_t stream) {
  (void)in_sizes; (void)n_in; (void)out_size; (void)ws_size;
  const float* x = (const float*)d_in[0];
  const float* w = (const float*)d_in[1];
  const int* label = (const int*)d_in[2];
  float* out = (float*)d_out;
  float* out1 = out + 1;                                  // output_sample [B, C]
  float* out2 = out + 1 + (size_t)BATCH * CCLS;           // output_center[label] [B, C]

  char* ws = (char*)d_ws;
  size_t o = 0;
  u16* xb = (u16*)(ws + o); o += (size_t)BATCH * KDIM * 2;   // x1 bf16
  u16* wb = (u16*)(ws + o); o += (size_t)CPAD * KDIM * 2;    // w bf16 (padded)
  u16* mb = (u16*)(ws + o); o += (size_t)CPAD * KDIM * 2;    // mean bf16 (padded)
  const size_t zo = o;                                       // ---- zeroed region ----
  float* sumx = (float*)(ws + o); o += (size_t)CCLS * KDIM * 4;
  float* cnts = (float*)(ws + o); o += (size_t)CPAD * 4;
  float* scal = (float*)(ws + o); o += 256;
  float* rowse_s = (float*)(ws + o); o += (size_t)BATCH * 4;
  float* rowsum_s = (float*)(ws + o); o += (size_t)BATCH * 4;
  float* rowse_c = (float*)(ws + o); o += (size_t)CPAD * 4;
  float* rowsum_c = (float*)(ws + o); o += (size_t)CPAD * 4;
  const size_t ze = o;                                       // ---- end zeroed ----
  float* rowtgt_s = (float*)(ws + o); o += (size_t)BATCH * 4;  // fully written before read
  float* rowtgt_c = (float*)(ws + o); o += (size_t)CPAD * 4;

  const int n4 = (int)((ze - zo) / 16);
  zero_k<<<(n4 + 255) / 256, 256, 0, stream>>>((f32x4*)(ws + zo), n4);

  norm_w_k<<<CPAD / 4, 256, 0, stream>>>(w, wb);
  norm_x_k<<<BATCH / 4, 256, 0, stream>>>(x, label, xb, sumx, cnts);
  mean_k<<<CPAD / 4, 256, 0, stream>>>(sumx, cnts, mb);

  gemm_k<0><<<dim3(47, 64), 256, 0, stream>>>(xb, wb, out1, label, scal, rowse_s, rowsum_s, rowtgt_s);
  gemm_k<1><<<dim3(47, 47), 256, 0, stream>>>(mb, wb, out2, label, scal, rowse_c, rowsum_c, rowtgt_c);
  gather_k<<<BATCH - CCLS, 256, 0, stream>>>(label, out2);

  ce_fin_k<<<BATCH / 256, 256, 0, stream>>>(rowse_s, rowsum_s, rowtgt_s, rowse_c, rowsum_c, rowtgt_c, scal);

  gemm_k<2><<<dim3(47, 47), 256, 0, stream>>>(mb, mb, nullptr, nullptr, scal, nullptr, nullptr, nullptr);
  gemm_k<3><<<dim3(47, 47), 256, 0, stream>>>(mb, mb, nullptr, nullptr, scal, nullptr, nullptr, nullptr);

  finalize_k<<<1, 1, 0, stream>>>(scal, out);
}

// Round 7
// 335.879 us; speedup vs baseline: 1.2852x; 1.0418x over previous
//
#include <hip/hip_runtime.h>
#include <cstdint>
#include <cstddef>

#define CCLS 5994
#define CPAD 6016
#define BATCH 8192
#define KDIM 192
#define EMAX 16
#define NCB 47   // col blocks

#define S_SC 30.0f
#define COSM 0.9800665778412416f
#define SINM 0.19866933079506122f
#define THC  0.9800665778412416f
#define MMC  0.039733866159012244f

typedef __attribute__((ext_vector_type(8))) short short8;
typedef __attribute__((ext_vector_type(4))) float f32x4;
typedef unsigned short u16;
typedef unsigned int u32;

__device__ __forceinline__ u16 f2bf(float f) {
  u32 u = __float_as_uint(f);
  u32 r = (u + 0x7FFFu + ((u >> 16) & 1u)) >> 16;
  return (u16)r;
}

__device__ __forceinline__ float bf2f(u16 v) {
  return __uint_as_float(((u32)v) << 16);
}

__device__ __forceinline__ float arc_phi(float c) {
  float s2 = fminf(fmaxf(1.0f - c * c, 0.0f), 1.0f);
  float sine = sqrtf(s2);
  return (c - THC > 0.0f) ? (c - MMC) : (c * COSM - sine * SINM);
}

__device__ __forceinline__ float shift_of(float vmax) {
  return (2.0f - vmax) * (1.0f + 2.0f / vmax);
}

__device__ __forceinline__ float wave_sum(float v) {
#pragma unroll
  for (int off = 1; off < 64; off <<= 1) v += __shfl_xor(v, off);
  return v;
}

// ---------------- fast zero ----------------
__global__ void zero_k(f32x4* __restrict__ p, int n4) {
  const int i = blockIdx.x * 256 + threadIdx.x;
  if (i < n4) p[i] = (f32x4){0.f, 0.f, 0.f, 0.f};
}

// ---------------- normalize weight -> bf16 (padded rows zeroed) ----------------
__global__ void norm_w_k(const float* __restrict__ w, u16* __restrict__ wb) {
  const int row = blockIdx.x * 4 + (threadIdx.x >> 6);
  const int lane = threadIdx.x & 63;
  float v0 = 0.f, v1 = 0.f, v2 = 0.f;
  if (row < CCLS) {
    const float* p = w + (size_t)row * KDIM;
    v0 = p[lane]; v1 = p[lane + 64]; v2 = p[lane + 128];
  }
  float ss = wave_sum(v0 * v0 + v1 * v1 + v2 * v2);
  float inv = 1.0f / fmaxf(sqrtf(ss), 1e-12f);
  if (row >= CCLS) inv = 0.f;
  u16* q = wb + (size_t)row * KDIM;
  q[lane] = f2bf(v0 * inv);
  q[lane + 64] = f2bf(v1 * inv);
  q[lane + 128] = f2bf(v2 * inv);
}

// ---------------- normalize x -> bf16 + build per-class inverse index (NO fp32 atomics) ----------------
__global__ void norm_x_k(const float* __restrict__ x, const int* __restrict__ label,
                         u16* __restrict__ xb, int* __restrict__ ecnt, int* __restrict__ eidx) {
  const int row = blockIdx.x * 4 + (threadIdx.x >> 6);
  const int lane = threadIdx.x & 63;
  const float* p = x + (size_t)row * KDIM;
  float v0 = p[lane], v1 = p[lane + 64], v2 = p[lane + 128];
  float ss = wave_sum(v0 * v0 + v1 * v1 + v2 * v2);
  float inv = 1.0f / fmaxf(sqrtf(ss), 1e-12f);
  u16* q = xb + (size_t)row * KDIM;
  q[lane] = f2bf(v0 * inv); q[lane + 64] = f2bf(v1 * inv); q[lane + 128] = f2bf(v2 * inv);
  if (lane == 0) {
    const int lab = label[row];
    int pos = atomicAdd(&ecnt[lab], 1);
    if (pos < EMAX) eidx[lab * EMAX + pos] = row;
  }
}

// ---------------- class means via gather (reads xb rows listed in eidx) ----------------
__global__ void mean_k(const u16* __restrict__ xb, const int* __restrict__ ecnt,
                       const int* __restrict__ eidx, u16* __restrict__ mb) {
  const int row = blockIdx.x * 4 + (threadIdx.x >> 6);
  const int lane = threadIdx.x & 63;
  u16* q = mb + (size_t)row * KDIM;
  if (row < CCLS) {
    const int n = min(ecnt[row], EMAX);
    float s0 = 0.f, s1 = 0.f, s2 = 0.f;
    for (int j = 0; j < n; ++j) {
      const u16* p = xb + (size_t)eidx[row * EMAX + j] * KDIM;
      s0 += bf2f(p[lane]); s1 += bf2f(p[lane + 64]); s2 += bf2f(p[lane + 128]);
    }
    const float inv = 1.0f / (float)n;
    q[lane] = f2bf(s0 * inv); q[lane + 64] = f2bf(s1 * inv); q[lane + 128] = f2bf(s2 * inv);
  } else {
    q[lane] = 0; q[lane + 64] = 0; q[lane + 128] = 0;
  }
}

// ---- stage one 128x32 bf16 tile pair (A,B) into LDS via global_load_lds (linear dest) ----
__device__ __forceinline__ void stage32(const u16* __restrict__ A, const u16* __restrict__ Bm,
                                        int row0, int col0, int wid, int lane, int k0,
                                        u16* As, u16* Bs) {
#pragma unroll
  for (int i = 0; i < 2; ++i) {
    const int c = wid * 2 + i;               // chunk 0..7, 16 rows each
    const int r = c * 16 + (lane >> 2);      // tile row 0..127
    const int cc = (lane & 3) * 8;           // tile col (bf16 units)
    const u16* ga = A + (size_t)(row0 + r) * KDIM + (k0 + cc);
    const u16* gb = Bm + (size_t)(col0 + r) * KDIM + (k0 + cc);
    __builtin_amdgcn_global_load_lds((const __attribute__((address_space(1))) void*)ga,
                                     (__attribute__((address_space(3))) void*)(As + c * 512),
                                     16, 0, 0);
    __builtin_amdgcn_global_load_lds((const __attribute__((address_space(1))) void*)gb,
                                     (__attribute__((address_space(3))) void*)(Bs + c * 512),
                                     16, 0, 0);
  }
}

// ---------------- GEMM: C = A(row-major [M,192]) * B(row-major [N,192])^T ----------------
// 32KB LDS exactly -> 5 blocks/CU. BK=32 double-buffer, counted vmcnt, raw s_barrier.
// MODE 0: ArcFace sample epilogue -> out + CE partial planes (NO atomics)
// MODE 1: ArcFace center epilogue -> out rows < CCLS + CE partial planes
// MODE 2: Gram stats pass1 (upper-tri): encoded vmax -> scal[0], sum exp(G-2) -> scal[1]
// MODE 3: Gram stats pass2 (upper-tri): sum exp(cco + aco*G) -> scal[2]
template <int MODE>
__launch_bounds__(256)
__global__ void gemm_k(const u16* __restrict__ A, const u16* __restrict__ Bm,
                       float* __restrict__ out, const int* __restrict__ label,
                       float* __restrict__ scal,
                       float* __restrict__ pse, float* __restrict__ psm,
                       float* __restrict__ rowtgt) {
  if (MODE >= 2 && blockIdx.y > blockIdx.x) return;  // symmetric Gram: upper-tri blocks only

  __shared__ u16 lds[2][2][4096];      // [buf][A/B][128x32 bf16] = 32768 B exactly
  float* sred = (float*)&lds[0][0][0]; // aliased; reused only after pipeline drains

  const int tid = threadIdx.x;
  const int lane = tid & 63;
  const int wid = tid >> 6;
  const int row0 = blockIdx.y * 128;
  const int col0 = blockIdx.x * 128;
  const int wm = wid >> 1;
  const int wn = wid & 1;

  float aco = 0.f, cco = 0.f;  // MODE 3: arg = cco + aco * g
  if (MODE == 3) {
    u32 u = __float_as_uint(scal[0]);
    u32 bits = (u & 0x80000000u) ? (u ^ 0x80000000u) : ~u;
    float vmax = __uint_as_float(bits);
    aco = -(2.0f - vmax) / vmax;
    cco = (2.0f - vmax) - shift_of(vmax);
  }

  f32x4 acc[4][4];
#pragma unroll
  for (int i = 0; i < 4; ++i)
#pragma unroll
    for (int j = 0; j < 4; ++j)
      acc[i][j] = (f32x4){0.f, 0.f, 0.f, 0.f};

  stage32(A, Bm, row0, col0, wid, lane, 0,  &lds[0][0][0], &lds[0][1][0]);
  stage32(A, Bm, row0, col0, wid, lane, 32, &lds[1][0][0], &lds[1][1][0]);

#define GSTEP(T, WN)                                                                         \
  {                                                                                          \
    asm volatile("s_waitcnt vmcnt(" #WN ")" ::: "memory");                                   \
    __builtin_amdgcn_s_barrier();                                                            \
    __builtin_amdgcn_sched_barrier(0);                                                       \
    const u16* Ab = &lds[(T) & 1][0][0];                                                     \
    const u16* Bb = &lds[(T) & 1][1][0];                                                     \
    short8 af[4], bf[4];                                                                     \
    _Pragma("unroll")                                                                        \
    for (int mi = 0; mi < 4; ++mi)                                                           \
      af[mi] = *(const short8*)&Ab[(wm * 64 + mi * 16 + (lane & 15)) * 32 + (lane >> 4) * 8]; \
    _Pragma("unroll")                                                                        \
    for (int ni = 0; ni < 4; ++ni)                                                           \
      bf[ni] = *(const short8*)&Bb[(wn * 64 + ni * 16 + (lane & 15)) * 32 + (lane >> 4) * 8]; \
    _Pragma("unroll")                                                                        \
    for (int mi = 0; mi < 4; ++mi)                                                           \
      _Pragma("unroll")                                                                      \
      for (int ni = 0; ni < 4; ++ni)                                                         \
        acc[mi][ni] = __builtin_amdgcn_mfma_f32_16x16x32_bf16(af[mi], bf[ni], acc[mi][ni], 0, 0, 0); \
    __builtin_amdgcn_sched_barrier(0);                                                       \
    __builtin_amdgcn_s_barrier();                                                            \
    __builtin_amdgcn_sched_barrier(0);                                                       \
    if ((T) < 4)                                                                             \
      stage32(A, Bm, row0, col0, wid, lane, ((T) + 2) * 32,                                  \
              &lds[(T) & 1][0][0], &lds[(T) & 1][1][0]);                                     \
  }

  GSTEP(0, 4) GSTEP(1, 4) GSTEP(2, 4) GSTEP(3, 4) GSTEP(4, 4) GSTEP(5, 0)
#undef GSTEP

  const int rl = (lane >> 4) * 4;  // C/D: row = (lane>>4)*4 + reg, col = lane&15
  const int cl = lane & 15;

  if (MODE == 0 || MODE == 1) {
    constexpr int PLANE = (MODE == 0) ? BATCH : CPAD;
#pragma unroll
    for (int mi = 0; mi < 4; ++mi) {
#pragma unroll
      for (int r = 0; r < 4; ++r) {
        const int gr = row0 + wm * 64 + mi * 16 + rl + r;  // uniform across the 16-lane group
        if (MODE == 1 && gr >= CCLS) continue;
        const int tgt = (MODE == 0) ? label[gr] : gr;
        float se = 0.f, sm = 0.f;
#pragma unroll
        for (int ni = 0; ni < 4; ++ni) {
          const int gc = col0 + wn * 64 + ni * 16 + cl;
          if (gc < CCLS) {
            float v = acc[mi][ni][r];
            float val = ((gc == tgt) ? arc_phi(v) : v) * S_SC;
            out[(size_t)gr * CCLS + gc] = val;
            se += __expf(val - 30.0f);
            sm += val;
            if (gc == tgt) rowtgt[gr] = val;  // unique writer
          }
        }
        // reduce across the 16-lane group sharing this row
#pragma unroll
        for (int m = 1; m < 16; m <<= 1) {
          se += __shfl_xor(se, m);
          sm += __shfl_xor(sm, m);
        }
        if (cl == 0) {
          const int lr = wm * 64 + mi * 16 + rl + r;  // 0..127 local row
          sred[lr * 2 + wn] = se;
          sred[256 + lr * 2 + wn] = sm;
        }
      }
    }
    __syncthreads();
    if (tid < 128) {
      const int gr = row0 + tid;
      if (MODE == 0 || gr < CCLS) {
        float se = sred[tid * 2] + sred[tid * 2 + 1];
        float sm = sred[256 + tid * 2] + sred[256 + tid * 2 + 1];
        pse[(size_t)blockIdx.x * PLANE + gr] = se;
        psm[(size_t)blockIdx.x * PLANE + gr] = sm;
      }
    }
  } else {
    float lsum = 0.f;
    float lmax = -3.0e38f;
#pragma unroll
    for (int mi = 0; mi < 4; ++mi)
#pragma unroll
      for (int r = 0; r < 4; ++r) {
        const int gi = row0 + wm * 64 + mi * 16 + rl + r;
#pragma unroll
        for (int ni = 0; ni < 4; ++ni) {
          const int gj = col0 + wn * 64 + ni * 16 + cl;
          if (gi < CCLS && gj < CCLS && gi != gj) {
            float g = 2.0f * acc[mi][ni][r];
            if (MODE == 2) {
              lsum += __expf(g - 2.0f);
              lmax = fmaxf(lmax, g);
            } else {
              lsum += __expf(fmaf(aco, g, cco));
            }
          }
        }
      }
    const float wgt = (blockIdx.x == blockIdx.y) ? 1.0f : 2.0f;  // off-diag counted twice
    lsum = wave_sum(lsum) * wgt;
    if (MODE == 2) {
#pragma unroll
      for (int off = 1; off < 64; off <<= 1) lmax = fmaxf(lmax, __shfl_xor(lmax, off));
    }
    __syncthreads();
    if (lane == 0) { sred[wid] = lsum; sred[4 + wid] = lmax; }
    __syncthreads();
    if (tid == 0) {
      float s = sred[0] + sred[1] + sred[2] + sred[3];
      atomicAdd(&scal[(MODE == 2) ? 1 : 2], s);
      if (MODE == 2) {
        float m = fmaxf(fmaxf(sred[4], sred[5]), fmaxf(sred[6], sred[7]));
        u32 b = __float_as_uint(m);
        u32 enc = (b & 0x80000000u) ? ~b : (b | 0x80000000u);
        atomicMax((u32*)&scal[0], enc);
      }
    }
  }
}

// ---------------- gather rows b >= CCLS: out2[b,:] = out2[label[b],:] ----------------
__global__ void gather_k(const int* __restrict__ label, float* __restrict__ out2) {
  const int b = CCLS + blockIdx.x;
  const int r = label[b];
  const float* src = out2 + (size_t)r * CCLS;
  float* dst = out2 + (size_t)b * CCLS;
  for (int j = threadIdx.x; j < CCLS; j += 256) dst[j] = src[j];
}

// ---------------- finalize CE from partial planes (no atomics upstream) ----------------
__global__ void ce_fin_k(const float* __restrict__ pse_s, const float* __restrict__ psm_s,
                         const float* __restrict__ rowtgt_s, const float* __restrict__ pse_c,
                         const float* __restrict__ psm_c, const float* __restrict__ rowtgt_c,
                         float* __restrict__ scal) {
  const int i = blockIdx.x * 256 + threadIdx.x;
  float ls = 0.f, lc = 0.f;
  if (i < BATCH) {
    float se = 0.f, sm = 0.f;
#pragma unroll 1
    for (int p = 0; p < NCB; ++p) { se += pse_s[p * BATCH + i]; sm += psm_s[p * BATCH + i]; }
    ls = 30.0f + logf(se) - 0.9f * rowtgt_s[i] - (0.1f / (float)CCLS) * sm;
  }
  if (i < CCLS) {
    float se = 0.f, sm = 0.f;
#pragma unroll 1
    for (int p = 0; p < NCB; ++p) { se += pse_c[p * CPAD + i]; sm += psm_c[p * CPAD + i]; }
    lc = 30.0f + logf(se) - 0.9f * rowtgt_c[i] - (0.1f / (float)CCLS) * sm;
  }
  ls = wave_sum(ls);
  lc = wave_sum(lc);
  if ((threadIdx.x & 63) == 0) {
    atomicAdd(&scal[3], ls);
    atomicAdd(&scal[4], lc);
  }
}

// ---------------- finalize loss ----------------
__global__ void finalize_k(const float* __restrict__ scal, float* __restrict__ out) {
  u32 u = __float_as_uint(scal[0]);
  u32 bits = (u & 0x80000000u) ? (u ^ 0x80000000u) : ~u;
  float vmax = __uint_as_float(bits);
  float s1 = scal[1], s2 = scal[2], ces = scal[3], cec = scal[4];
  float lse1 = 2.0f + logf(s1);
  float lse2 = shift_of(vmax) + logf(s2);
  float z = lse1 - lse2 + vmax;
  float sp = (z > 20.f) ? z : log1pf(expf(z));
  out[0] = sp + 0.5f * (cec / (float)CCLS) + 0.5f * (ces / (float)BATCH);
}

extern "C" void kernel_launch(void* const* d_in, const int* in_sizes, int n_in,
                              void* d_out, int out_size, void* d_ws, size_t ws_size,
                              hipStream_t stream) {
  (void)in_sizes; (void)n_in; (void)out_size; (void)ws_size;
  const float* x = (const float*)d_in[0];
  const float* w = (const float*)d_in[1];
  const int* label = (const int*)d_in[2];
  float* out = (float*)d_out;
  float* out1 = out + 1;                                  // output_sample [B, C]
  float* out2 = out + 1 + (size_t)BATCH * CCLS;           // output_center[label] [B, C]

  char* ws = (char*)d_ws;
  size_t o = 0;
  u16* xb = (u16*)(ws + o); o += (size_t)BATCH * KDIM * 2;   // x1 bf16
  u16* wb = (u16*)(ws + o); o += (size_t)CPAD * KDIM * 2;    // w bf16 (padded)
  u16* mb = (u16*)(ws + o); o += (size_t)CPAD * KDIM * 2;    // mean bf16 (padded)
  const size_t zo = o;                                       // ---- zeroed region ----
  float* scal = (float*)(ws + o); o += 256;
  int* ecnt = (int*)(ws + o); o += (size_t)CPAD * 4;
  const size_t ze = o;                                       // ---- end zeroed ----
  int* eidx = (int*)(ws + o); o += (size_t)CPAD * EMAX * 4;
  float* rowtgt_s = (float*)(ws + o); o += (size_t)BATCH * 4;  // written before read
  float* rowtgt_c = (float*)(ws + o); o += (size_t)CPAD * 4;
  float* pse_s = (float*)(ws + o); o += (size_t)NCB * BATCH * 4;
  float* psm_s = (float*)(ws + o); o += (size_t)NCB * BATCH * 4;
  float* pse_c = (float*)(ws + o); o += (size_t)NCB * CPAD * 4;
  float* psm_c = (float*)(ws + o); o += (size_t)NCB * CPAD * 4;

  const int n4 = (int)((ze - zo) / 16);
  zero_k<<<(n4 + 255) / 256, 256, 0, stream>>>((f32x4*)(ws + zo), n4);

  norm_w_k<<<CPAD / 4, 256, 0, stream>>>(w, wb);
  norm_x_k<<<BATCH / 4, 256, 0, stream>>>(x, label, xb, ecnt, eidx);
  mean_k<<<CPAD / 4, 256, 0, stream>>>(xb, ecnt, eidx, mb);

  gemm_k<0><<<dim3(NCB, 64), 256, 0, stream>>>(xb, wb, out1, label, scal, pse_s, psm_s, rowtgt_s);
  gemm_k<1><<<dim3(NCB, NCB), 256, 0, stream>>>(mb, wb, out2, label, scal, pse_c, psm_c, rowtgt_c);
  gather_k<<<BATCH - CCLS, 256, 0, stream>>>(label, out2);

  ce_fin_k<<<BATCH / 256, 256, 0, stream>>>(pse_s, psm_s, rowtgt_s, pse_c, psm_c, rowtgt_c, scal);

  gemm_k<2><<<dim3(NCB, NCB), 256, 0, stream>>>(mb, mb, nullptr, nullptr, scal, nullptr, nullptr, nullptr);
  gemm_k<3><<<dim3(NCB, NCB), 256, 0, stream>>>(mb, mb, nullptr, nullptr, scal, nullptr, nullptr, nullptr);

  finalize_k<<<1, 1, 0, stream>>>(scal, out);
}

// Round 8
// 312.283 us; speedup vs baseline: 1.3823x; 1.0756x over previous
//
#include <hip/hip_runtime.h>
#include <cstdint>
#include <cstddef>

#define CCLS 5994
#define CPAD 6016
#define BATCH 8192
#define KDIM 192
#define EMAX 16
#define NCB 47   // col blocks

#define S_SC 30.0f
#define COSM 0.9800665778412416f
#define SINM 0.19866933079506122f
#define THC  0.9800665778412416f
#define MMC  0.039733866159012244f

typedef __attribute__((ext_vector_type(8))) short short8;
typedef __attribute__((ext_vector_type(4))) float f32x4;
typedef __attribute__((ext_vector_type(2))) float f32x2;
typedef unsigned short u16;
typedef unsigned int u32;

__device__ __forceinline__ u16 f2bf(float f) {
  u32 u = __float_as_uint(f);
  u32 r = (u + 0x7FFFu + ((u >> 16) & 1u)) >> 16;
  return (u16)r;
}

__device__ __forceinline__ float bf2f(u16 v) {
  return __uint_as_float(((u32)v) << 16);
}

__device__ __forceinline__ float arc_phi(float c) {
  float s2 = fminf(fmaxf(1.0f - c * c, 0.0f), 1.0f);
  float sine = sqrtf(s2);
  return (c - THC > 0.0f) ? (c - MMC) : (c * COSM - sine * SINM);
}

__device__ __forceinline__ float shift_of(float vmax) {
  return (2.0f - vmax) * (1.0f + 2.0f / vmax);
}

__device__ __forceinline__ float wave_sum(float v) {
#pragma unroll
  for (int off = 1; off < 64; off <<= 1) v += __shfl_xor(v, off);
  return v;
}

// m204 bijective XCD-chunked remap: contiguous logical blocks land on one XCD's L2.
__device__ __forceinline__ void remap_xcd(int nbx, int nby, int& bx, int& by) {
  const int nwg = nbx * nby;
  const int orig = blockIdx.y * nbx + blockIdx.x;
  const int q = nwg >> 3, r = nwg & 7;
  const int xcd = orig & 7, idx = orig >> 3;
  const int neu = (xcd < r ? xcd * (q + 1) : r * (q + 1) + (xcd - r) * q) + idx;
  bx = neu % nbx;
  by = neu / nbx;
}

// ---------------- fast zero ----------------
__global__ void zero_k(f32x4* __restrict__ p, int n4) {
  const int i = blockIdx.x * 256 + threadIdx.x;
  if (i < n4) p[i] = (f32x4){0.f, 0.f, 0.f, 0.f};
}

// ---------------- normalize weight -> bf16 (padded rows zeroed) ----------------
__global__ void norm_w_k(const float* __restrict__ w, u16* __restrict__ wb) {
  const int row = blockIdx.x * 4 + (threadIdx.x >> 6);
  const int lane = threadIdx.x & 63;
  float v0 = 0.f, v1 = 0.f, v2 = 0.f;
  if (row < CCLS) {
    const float* p = w + (size_t)row * KDIM;
    v0 = p[lane]; v1 = p[lane + 64]; v2 = p[lane + 128];
  }
  float ss = wave_sum(v0 * v0 + v1 * v1 + v2 * v2);
  float inv = 1.0f / fmaxf(sqrtf(ss), 1e-12f);
  if (row >= CCLS) inv = 0.f;
  u16* q = wb + (size_t)row * KDIM;
  q[lane] = f2bf(v0 * inv);
  q[lane + 64] = f2bf(v1 * inv);
  q[lane + 128] = f2bf(v2 * inv);
}

// ---------------- normalize x -> bf16 + per-class inverse index ----------------
__global__ void norm_x_k(const float* __restrict__ x, const int* __restrict__ label,
                         u16* __restrict__ xb, int* __restrict__ ecnt, int* __restrict__ eidx) {
  const int row = blockIdx.x * 4 + (threadIdx.x >> 6);
  const int lane = threadIdx.x & 63;
  const float* p = x + (size_t)row * KDIM;
  float v0 = p[lane], v1 = p[lane + 64], v2 = p[lane + 128];
  float ss = wave_sum(v0 * v0 + v1 * v1 + v2 * v2);
  float inv = 1.0f / fmaxf(sqrtf(ss), 1e-12f);
  u16* q = xb + (size_t)row * KDIM;
  q[lane] = f2bf(v0 * inv); q[lane + 64] = f2bf(v1 * inv); q[lane + 128] = f2bf(v2 * inv);
  if (lane == 0) {
    const int lab = label[row];
    int pos = atomicAdd(&ecnt[lab], 1);
    if (pos < EMAX) eidx[lab * EMAX + pos] = row;
  }
}

// ---------------- class means via gather ----------------
__global__ void mean_k(const u16* __restrict__ xb, const int* __restrict__ ecnt,
                       const int* __restrict__ eidx, u16* __restrict__ mb) {
  const int row = blockIdx.x * 4 + (threadIdx.x >> 6);
  const int lane = threadIdx.x & 63;
  u16* q = mb + (size_t)row * KDIM;
  if (row < CCLS) {
    const int n = min(ecnt[row], EMAX);
    float s0 = 0.f, s1 = 0.f, s2 = 0.f;
    for (int j = 0; j < n; ++j) {
      const u16* p = xb + (size_t)eidx[row * EMAX + j] * KDIM;
      s0 += bf2f(p[lane]); s1 += bf2f(p[lane + 64]); s2 += bf2f(p[lane + 128]);
    }
    const float inv = 1.0f / (float)n;
    q[lane] = f2bf(s0 * inv); q[lane + 64] = f2bf(s1 * inv); q[lane + 128] = f2bf(s2 * inv);
  } else {
    q[lane] = 0; q[lane + 64] = 0; q[lane + 128] = 0;
  }
}

// ---- stage one 128x32 bf16 tile pair (A,B) into LDS via global_load_lds (linear dest) ----
__device__ __forceinline__ void stage32(const u16* __restrict__ A, const u16* __restrict__ Bm,
                                        int row0, int col0, int wid, int lane, int k0,
                                        u16* As, u16* Bs) {
#pragma unroll
  for (int i = 0; i < 2; ++i) {
    const int c = wid * 2 + i;               // chunk 0..7, 16 rows each
    const int r = c * 16 + (lane >> 2);      // tile row 0..127
    const int cc = (lane & 3) * 8;           // tile col (bf16 units)
    const u16* ga = A + (size_t)(row0 + r) * KDIM + (k0 + cc);
    const u16* gb = Bm + (size_t)(col0 + r) * KDIM + (k0 + cc);
    __builtin_amdgcn_global_load_lds((const __attribute__((address_space(1))) void*)ga,
                                     (__attribute__((address_space(3))) void*)(As + c * 512),
                                     16, 0, 0);
    __builtin_amdgcn_global_load_lds((const __attribute__((address_space(1))) void*)gb,
                                     (__attribute__((address_space(3))) void*)(Bs + c * 512),
                                     16, 0, 0);
  }
}

// ---------------- GEMM: C = A(row-major [M,192]) * B(row-major [N,192])^T ----------------
// 32KB LDS -> 5 blocks/CU. BK=32 dbuf, counted vmcnt. Epilogue: LDS-staged coalesced
// nontemporal dwordx2 row stores (old path: scalar stores, 4 misaligned 64B segs/instr ->
// partial-line RMW + L2 thrash; R3 WRITE amplification +32%).
// MODE 0: ArcFace sample -> out1 + CE partial planes    MODE 1: center -> out2 + planes
// MODE 2: Gram pass1 (upper-tri): vmax, sum exp(G-2)    MODE 3: Gram pass2: sum exp(cco+aco*G)
template <int MODE>
__launch_bounds__(256)
__global__ void gemm_k(const u16* __restrict__ A, const u16* __restrict__ Bm,
                       float* __restrict__ out, const int* __restrict__ label,
                       float* __restrict__ scal,
                       float* __restrict__ pse, float* __restrict__ psm,
                       float* __restrict__ rowtgt, int nby) {
  int bx, by;
  remap_xcd(NCB, nby, bx, by);
  if (MODE >= 2 && by > bx) return;  // symmetric Gram: upper-tri blocks only

  __shared__ u16 lds[2][2][4096];      // [buf][A/B][128x32 bf16] = 32768 B exactly
  float* sred = (float*)&lds[0][0][0]; // aliased after K-loop drains

  const int tid = threadIdx.x;
  const int lane = tid & 63;
  const int wid = tid >> 6;
  const int row0 = by * 128;
  const int col0 = bx * 128;
  const int wm = wid >> 1;
  const int wn = wid & 1;

  float aco = 0.f, cco = 0.f;  // MODE 3: arg = cco + aco * g
  if (MODE == 3) {
    u32 u = __float_as_uint(scal[0]);
    u32 bits = (u & 0x80000000u) ? (u ^ 0x80000000u) : ~u;
    float vmax = __uint_as_float(bits);
    aco = -(2.0f - vmax) / vmax;
    cco = (2.0f - vmax) - shift_of(vmax);
  }

  f32x4 acc[4][4];
#pragma unroll
  for (int i = 0; i < 4; ++i)
#pragma unroll
    for (int j = 0; j < 4; ++j)
      acc[i][j] = (f32x4){0.f, 0.f, 0.f, 0.f};

  stage32(A, Bm, row0, col0, wid, lane, 0,  &lds[0][0][0], &lds[0][1][0]);
  stage32(A, Bm, row0, col0, wid, lane, 32, &lds[1][0][0], &lds[1][1][0]);

#define GSTEP(T, WN)                                                                         \
  {                                                                                          \
    asm volatile("s_waitcnt vmcnt(" #WN ")" ::: "memory");                                   \
    __builtin_amdgcn_s_barrier();                                                            \
    __builtin_amdgcn_sched_barrier(0);                                                       \
    const u16* Ab = &lds[(T) & 1][0][0];                                                     \
    const u16* Bb = &lds[(T) & 1][1][0];                                                     \
    short8 af[4], bf[4];                                                                     \
    _Pragma("unroll")                                                                        \
    for (int mi = 0; mi < 4; ++mi)                                                           \
      af[mi] = *(const short8*)&Ab[(wm * 64 + mi * 16 + (lane & 15)) * 32 + (lane >> 4) * 8]; \
    _Pragma("unroll")                                                                        \
    for (int ni = 0; ni < 4; ++ni)                                                           \
      bf[ni] = *(const short8*)&Bb[(wn * 64 + ni * 16 + (lane & 15)) * 32 + (lane >> 4) * 8]; \
    _Pragma("unroll")                                                                        \
    for (int mi = 0; mi < 4; ++mi)                                                           \
      _Pragma("unroll")                                                                      \
      for (int ni = 0; ni < 4; ++ni)                                                         \
        acc[mi][ni] = __builtin_amdgcn_mfma_f32_16x16x32_bf16(af[mi], bf[ni], acc[mi][ni], 0, 0, 0); \
    __builtin_amdgcn_sched_barrier(0);                                                       \
    __builtin_amdgcn_s_barrier();                                                            \
    __builtin_amdgcn_sched_barrier(0);                                                       \
    if ((T) < 4)                                                                             \
      stage32(A, Bm, row0, col0, wid, lane, ((T) + 2) * 32,                                  \
              &lds[(T) & 1][0][0], &lds[(T) & 1][1][0]);                                     \
  }

  GSTEP(0, 4) GSTEP(1, 4) GSTEP(2, 4) GSTEP(3, 4) GSTEP(4, 4) GSTEP(5, 0)
#undef GSTEP

  const int rl = (lane >> 4) * 4;  // C/D: row = (lane>>4)*4 + reg, col = lane&15
  const int cl = lane & 15;

  if (MODE == 0 || MODE == 1) {
    constexpr int PLANE = (MODE == 0) ? BATCH : CPAD;
    // (1) transform acc in place (ArcFace * S), accumulate CE row stats
#pragma unroll
    for (int mi = 0; mi < 4; ++mi) {
#pragma unroll
      for (int r = 0; r < 4; ++r) {
        const int gr = row0 + wm * 64 + mi * 16 + rl + r;  // uniform across 16-lane group
        const int tgt = (MODE == 0) ? label[gr] : gr;      // (gr<BATCH always; MODE1 pad rows unused)
        float se = 0.f, sm = 0.f;
#pragma unroll
        for (int ni = 0; ni < 4; ++ni) {
          const int gc = col0 + wn * 64 + ni * 16 + cl;
          float v = acc[mi][ni][r];
          float val = ((gc == tgt) ? arc_phi(v) : v) * S_SC;
          acc[mi][ni][r] = val;
          if (gc < CCLS && (MODE == 0 || gr < CCLS)) {
            se += __expf(val - 30.0f);
            sm += val;
            if (gc == tgt) rowtgt[gr] = val;  // unique writer
          }
        }
#pragma unroll
        for (int m = 1; m < 16; m <<= 1) {
          se += __shfl_xor(se, m);
          sm += __shfl_xor(sm, m);
        }
        if (cl == 0) {
          const int lr = wm * 64 + mi * 16 + rl + r;  // local row 0..127
          sred[lr * 2 + wn] = se;
          sred[256 + lr * 2 + wn] = sm;
        }
      }
    }
    __syncthreads();
    // (2) combine wn halves -> partial planes
    if (tid < 128) {
      const int gr = row0 + tid;
      if (MODE == 0 || gr < CCLS) {
        float se = sred[tid * 2] + sred[tid * 2 + 1];
        float sm = sred[256 + tid * 2] + sred[256 + tid * 2 + 1];
        pse[(size_t)bx * PLANE + gr] = se;
        psm[(size_t)bx * PLANE + gr] = sm;
      }
    }
    // (3) LDS-staged coalesced row stores, two 64-row halves (32KB each)
    float* sC = (float*)&lds[0][0][0];  // [64][128] f32
#pragma unroll
    for (int half = 0; half < 2; ++half) {
      __syncthreads();
      if (wm == half) {
#pragma unroll
        for (int mi = 0; mi < 4; ++mi)
#pragma unroll
          for (int ni = 0; ni < 4; ++ni)
#pragma unroll
            for (int r = 0; r < 4; ++r)
              sC[(mi * 16 + rl + r) * 128 + wn * 64 + ni * 16 + cl] = acc[mi][ni][r];
      }
      __syncthreads();
#pragma unroll
      for (int i = 0; i < 16; ++i) {
        const int lr = wid * 16 + i;
        const int gr = row0 + half * 64 + lr;
        if (MODE == 1 && gr >= CCLS) continue;
        const int gc = col0 + lane * 2;
        if (gc < CCLS) {  // CCLS even, pairs never straddle
          f32x2 v = *(const f32x2*)&sC[lr * 128 + lane * 2];
          __builtin_nontemporal_store(v, (f32x2*)(out + (size_t)gr * CCLS + gc));
        }
      }
    }
  } else {
    float lsum = 0.f;
    float lmax = -3.0e38f;
#pragma unroll
    for (int mi = 0; mi < 4; ++mi)
#pragma unroll
      for (int r = 0; r < 4; ++r) {
        const int gi = row0 + wm * 64 + mi * 16 + rl + r;
#pragma unroll
        for (int ni = 0; ni < 4; ++ni) {
          const int gj = col0 + wn * 64 + ni * 16 + cl;
          if (gi < CCLS && gj < CCLS && gi != gj) {
            float g = 2.0f * acc[mi][ni][r];
            if (MODE == 2) {
              lsum += __expf(g - 2.0f);
              lmax = fmaxf(lmax, g);
            } else {
              lsum += __expf(fmaf(aco, g, cco));
            }
          }
        }
      }
    const float wgt = (bx == by) ? 1.0f : 2.0f;  // off-diag counted twice
    lsum = wave_sum(lsum) * wgt;
    if (MODE == 2) {
#pragma unroll
      for (int off = 1; off < 64; off <<= 1) lmax = fmaxf(lmax, __shfl_xor(lmax, off));
    }
    __syncthreads();
    if (lane == 0) { sred[wid] = lsum; sred[4 + wid] = lmax; }
    __syncthreads();
    if (tid == 0) {
      float s = sred[0] + sred[1] + sred[2] + sred[3];
      atomicAdd(&scal[(MODE == 2) ? 1 : 2], s);
      if (MODE == 2) {
        float m = fmaxf(fmaxf(sred[4], sred[5]), fmaxf(sred[6], sred[7]));
        u32 b = __float_as_uint(m);
        u32 enc = (b & 0x80000000u) ? ~b : (b | 0x80000000u);
        atomicMax((u32*)&scal[0], enc);
      }
    }
  }
}

// ---------------- gather rows b >= CCLS: out2[b,:] = out2[label[b],:] (vectorized) ----------------
__global__ void gather_k(const int* __restrict__ label, float* __restrict__ out2) {
  const int b = CCLS + blockIdx.x;
  const int r = label[b];
  const f32x2* src = (const f32x2*)(out2 + (size_t)r * CCLS);
  f32x2* dst = (f32x2*)(out2 + (size_t)b * CCLS);
  for (int j = threadIdx.x; j < CCLS / 2; j += 256)
    __builtin_nontemporal_store(src[j], &dst[j]);
}

// ---------------- finalize CE from partial planes ----------------
__global__ void ce_fin_k(const float* __restrict__ pse_s, const float* __restrict__ psm_s,
                         const float* __restrict__ rowtgt_s, const float* __restrict__ pse_c,
                         const float* __restrict__ psm_c, const float* __restrict__ rowtgt_c,
                         float* __restrict__ scal) {
  const int i = blockIdx.x * 256 + threadIdx.x;
  float ls = 0.f, lc = 0.f;
  if (i < BATCH) {
    float se = 0.f, sm = 0.f;
#pragma unroll 1
    for (int p = 0; p < NCB; ++p) { se += pse_s[p * BATCH + i]; sm += psm_s[p * BATCH + i]; }
    ls = 30.0f + logf(se) - 0.9f * rowtgt_s[i] - (0.1f / (float)CCLS) * sm;
  }
  if (i < CCLS) {
    float se = 0.f, sm = 0.f;
#pragma unroll 1
    for (int p = 0; p < NCB; ++p) { se += pse_c[p * CPAD + i]; sm += psm_c[p * CPAD + i]; }
    lc = 30.0f + logf(se) - 0.9f * rowtgt_c[i] - (0.1f / (float)CCLS) * sm;
  }
  ls = wave_sum(ls);
  lc = wave_sum(lc);
  if ((threadIdx.x & 63) == 0) {
    atomicAdd(&scal[3], ls);
    atomicAdd(&scal[4], lc);
  }
}

// ---------------- finalize loss ----------------
__global__ void finalize_k(const float* __restrict__ scal, float* __restrict__ out) {
  u32 u = __float_as_uint(scal[0]);
  u32 bits = (u & 0x80000000u) ? (u ^ 0x80000000u) : ~u;
  float vmax = __uint_as_float(bits);
  float s1 = scal[1], s2 = scal[2], ces = scal[3], cec = scal[4];
  float lse1 = 2.0f + logf(s1);
  float lse2 = shift_of(vmax) + logf(s2);
  float z = lse1 - lse2 + vmax;
  float sp = (z > 20.f) ? z : log1pf(expf(z));
  out[0] = sp + 0.5f * (cec / (float)CCLS) + 0.5f * (ces / (float)BATCH);
}

extern "C" void kernel_launch(void* const* d_in, const int* in_sizes, int n_in,
                              void* d_out, int out_size, void* d_ws, size_t ws_size,
                              hipStream_t stream) {
  (void)in_sizes; (void)n_in; (void)out_size; (void)ws_size;
  const float* x = (const float*)d_in[0];
  const float* w = (const float*)d_in[1];
  const int* label = (const int*)d_in[2];
  float* out = (float*)d_out;
  float* out1 = out + 1;                                  // output_sample [B, C]
  float* out2 = out + 1 + (size_t)BATCH * CCLS;           // output_center[label] [B, C]

  char* ws = (char*)d_ws;
  size_t o = 0;
  u16* xb = (u16*)(ws + o); o += (size_t)BATCH * KDIM * 2;   // x1 bf16
  u16* wb = (u16*)(ws + o); o += (size_t)CPAD * KDIM * 2;    // w bf16 (padded)
  u16* mb = (u16*)(ws + o); o += (size_t)CPAD * KDIM * 2;    // mean bf16 (padded)
  const size_t zo = o;                                       // ---- zeroed region ----
  float* scal = (float*)(ws + o); o += 256;
  int* ecnt = (int*)(ws + o); o += (size_t)CPAD * 4;
  const size_t ze = o;                                       // ---- end zeroed ----
  int* eidx = (int*)(ws + o); o += (size_t)CPAD * EMAX * 4;
  float* rowtgt_s = (float*)(ws + o); o += (size_t)BATCH * 4;  // written before read
  float* rowtgt_c = (float*)(ws + o); o += (size_t)CPAD * 4;
  float* pse_s = (float*)(ws + o); o += (size_t)NCB * BATCH * 4;
  float* psm_s = (float*)(ws + o); o += (size_t)NCB * BATCH * 4;
  float* pse_c = (float*)(ws + o); o += (size_t)NCB * CPAD * 4;
  float* psm_c = (float*)(ws + o); o += (size_t)NCB * CPAD * 4;

  const int n4 = (int)((ze - zo) / 16);
  zero_k<<<(n4 + 255) / 256, 256, 0, stream>>>((f32x4*)(ws + zo), n4);

  norm_w_k<<<CPAD / 4, 256, 0, stream>>>(w, wb);
  norm_x_k<<<BATCH / 4, 256, 0, stream>>>(x, label, xb, ecnt, eidx);
  mean_k<<<CPAD / 4, 256, 0, stream>>>(xb, ecnt, eidx, mb);

  gemm_k<0><<<dim3(NCB, 64), 256, 0, stream>>>(xb, wb, out1, label, scal, pse_s, psm_s, rowtgt_s, 64);
  gemm_k<1><<<dim3(NCB, NCB), 256, 0, stream>>>(mb, wb, out2, label, scal, pse_c, psm_c, rowtgt_c, NCB);
  gather_k<<<BATCH - CCLS, 256, 0, stream>>>(label, out2);

  ce_fin_k<<<BATCH / 256, 256, 0, stream>>>(pse_s, psm_s, rowtgt_s, pse_c, psm_c, rowtgt_c, scal);

  gemm_k<2><<<dim3(NCB, NCB), 256, 0, stream>>>(mb, mb, nullptr, nullptr, scal, nullptr, nullptr, nullptr, NCB);
  gemm_k<3><<<dim3(NCB, NCB), 256, 0, stream>>>(mb, mb, nullptr, nullptr, scal, nullptr, nullptr, nullptr, NCB);

  finalize_k<<<1, 1, 0, stream>>>(scal, out);
}

// Round 9
// 308.674 us; speedup vs baseline: 1.3984x; 1.0117x over previous
//
#include <hip/hip_runtime.h>
#include <cstdint>
#include <cstddef>

#define CCLS 5994
#define CPAD 6016
#define BATCH 8192
#define KDIM 192
#define EMAX 16
#define NCB 47   // col blocks

#define S_SC 30.0f
#define COSM 0.9800665778412416f
#define SINM 0.19866933079506122f
#define THC  0.9800665778412416f
#define MMC  0.039733866159012244f

typedef __attribute__((ext_vector_type(8))) short short8;
typedef __attribute__((ext_vector_type(4))) float f32x4;
typedef __attribute__((ext_vector_type(2))) float f32x2;
typedef unsigned short u16;
typedef unsigned int u32;

__device__ __forceinline__ u16 f2bf(float f) {
  u32 u = __float_as_uint(f);
  u32 r = (u + 0x7FFFu + ((u >> 16) & 1u)) >> 16;
  return (u16)r;
}

__device__ __forceinline__ float bf2f(u16 v) {
  return __uint_as_float(((u32)v) << 16);
}

__device__ __forceinline__ float arc_phi(float c) {
  float s2 = fminf(fmaxf(1.0f - c * c, 0.0f), 1.0f);
  float sine = sqrtf(s2);
  return (c - THC > 0.0f) ? (c - MMC) : (c * COSM - sine * SINM);
}

__device__ __forceinline__ float shift_of(float vmax) {
  return (2.0f - vmax) * (1.0f + 2.0f / vmax);
}

__device__ __forceinline__ float wave_sum(float v) {
#pragma unroll
  for (int off = 1; off < 64; off <<= 1) v += __shfl_xor(v, off);
  return v;
}

// m204 bijective XCD-chunked remap: contiguous logical blocks land on one XCD's L2.
__device__ __forceinline__ void remap_xcd(int nbx, int nby, int& bx, int& by) {
  const int nwg = nbx * nby;
  const int orig = blockIdx.y * nbx + blockIdx.x;
  const int q = nwg >> 3, r = nwg & 7;
  const int xcd = orig & 7, idx = orig >> 3;
  const int neu = (xcd < r ? xcd * (q + 1) : r * (q + 1) + (xcd - r) * q) + idx;
  bx = neu % nbx;
  by = neu / nbx;
}

// ---------------- fast zero ----------------
__global__ void zero_k(f32x4* __restrict__ p, int n4) {
  const int i = blockIdx.x * 256 + threadIdx.x;
  if (i < n4) p[i] = (f32x4){0.f, 0.f, 0.f, 0.f};
}

// ---------------- normalize weight -> bf16 (padded rows zeroed) ----------------
__global__ void norm_w_k(const float* __restrict__ w, u16* __restrict__ wb) {
  const int row = blockIdx.x * 4 + (threadIdx.x >> 6);
  const int lane = threadIdx.x & 63;
  float v0 = 0.f, v1 = 0.f, v2 = 0.f;
  if (row < CCLS) {
    const float* p = w + (size_t)row * KDIM;
    v0 = p[lane]; v1 = p[lane + 64]; v2 = p[lane + 128];
  }
  float ss = wave_sum(v0 * v0 + v1 * v1 + v2 * v2);
  float inv = 1.0f / fmaxf(sqrtf(ss), 1e-12f);
  if (row >= CCLS) inv = 0.f;
  u16* q = wb + (size_t)row * KDIM;
  q[lane] = f2bf(v0 * inv);
  q[lane + 64] = f2bf(v1 * inv);
  q[lane + 128] = f2bf(v2 * inv);
}

// ---------------- normalize x -> bf16 + per-class inverse index ----------------
__global__ void norm_x_k(const float* __restrict__ x, const int* __restrict__ label,
                         u16* __restrict__ xb, int* __restrict__ ecnt, int* __restrict__ eidx) {
  const int row = blockIdx.x * 4 + (threadIdx.x >> 6);
  const int lane = threadIdx.x & 63;
  const float* p = x + (size_t)row * KDIM;
  float v0 = p[lane], v1 = p[lane + 64], v2 = p[lane + 128];
  float ss = wave_sum(v0 * v0 + v1 * v1 + v2 * v2);
  float inv = 1.0f / fmaxf(sqrtf(ss), 1e-12f);
  u16* q = xb + (size_t)row * KDIM;
  q[lane] = f2bf(v0 * inv); q[lane + 64] = f2bf(v1 * inv); q[lane + 128] = f2bf(v2 * inv);
  if (lane == 0) {
    const int lab = label[row];
    int pos = atomicAdd(&ecnt[lab], 1);
    if (pos < EMAX) eidx[lab * EMAX + pos] = row;
  }
}

// ---------------- class means via gather ----------------
__global__ void mean_k(const u16* __restrict__ xb, const int* __restrict__ ecnt,
                       const int* __restrict__ eidx, u16* __restrict__ mb) {
  const int row = blockIdx.x * 4 + (threadIdx.x >> 6);
  const int lane = threadIdx.x & 63;
  u16* q = mb + (size_t)row * KDIM;
  if (row < CCLS) {
    const int n = min(ecnt[row], EMAX);
    float s0 = 0.f, s1 = 0.f, s2 = 0.f;
    for (int j = 0; j < n; ++j) {
      const u16* p = xb + (size_t)eidx[row * EMAX + j] * KDIM;
      s0 += bf2f(p[lane]); s1 += bf2f(p[lane + 64]); s2 += bf2f(p[lane + 128]);
    }
    const float inv = 1.0f / (float)n;
    q[lane] = f2bf(s0 * inv); q[lane + 64] = f2bf(s1 * inv); q[lane + 128] = f2bf(s2 * inv);
  } else {
    q[lane] = 0; q[lane + 64] = 0; q[lane + 128] = 0;
  }
}

// ---- stage one 128x64 bf16 tile pair into LDS, XOR-swizzled via pre-swizzled GLOBAL src ----
// LDS dest is linear (global_load_lds requirement). LDS[row][slot] holds global 16B-slot
// (slot ^ (row&7)) of the row. Fragment reads use the same XOR -> 2 lanes/bank (free).
__device__ __forceinline__ void stage64(const u16* __restrict__ A, const u16* __restrict__ Bm,
                                        int row0, int col0, int wid, int lane, int k0,
                                        u16* As, u16* Bs) {
  const int sw = (((lane & 7) ^ ((lane >> 3) & 7))) * 8;  // swizzled 16B slot, u16 units
#pragma unroll
  for (int i = 0; i < 4; ++i) {
    const int c = wid * 4 + i;               // chunk 0..15, 1024B = 8 rows
    const int r = c * 8 + (lane >> 3);       // tile row 0..127 (row&7 == (lane>>3)&7)
    const u16* ga = A + (size_t)(row0 + r) * KDIM + (k0 + sw);
    const u16* gb = Bm + (size_t)(col0 + r) * KDIM + (k0 + sw);
    __builtin_amdgcn_global_load_lds((const __attribute__((address_space(1))) void*)ga,
                                     (__attribute__((address_space(3))) void*)(As + c * 512),
                                     16, 0, 0);
    __builtin_amdgcn_global_load_lds((const __attribute__((address_space(1))) void*)gb,
                                     (__attribute__((address_space(3))) void*)(Bs + c * 512),
                                     16, 0, 0);
  }
}

// ---------------- GEMM: C = A(row-major [M,192]) * B(row-major [N,192])^T ----------------
// 32KB LDS (BK=64 single-buffer) -> 5 blocks/CU. LDS XOR-swizzle: fragment ds_read_b128
// was 16-way bank-conflicted (5.69x, the dominant per-block cost); now conflict-free.
// Epilogue: LDS-staged coalesced nontemporal stores (R8).
// MODE 0: ArcFace sample -> out1 + CE partial planes    MODE 1: center -> out2 + planes
// MODE 2: Gram pass1 (upper-tri): vmax, sum exp(G-2)    MODE 3: Gram pass2: sum exp(cco+aco*G)
template <int MODE>
__launch_bounds__(256)
__global__ void gemm_k(const u16* __restrict__ A, const u16* __restrict__ Bm,
                       float* __restrict__ out, const int* __restrict__ label,
                       float* __restrict__ scal,
                       float* __restrict__ pse, float* __restrict__ psm,
                       float* __restrict__ rowtgt, int nby) {
  int bx, by;
  remap_xcd(NCB, nby, bx, by);
  if (MODE >= 2 && by > bx) return;  // symmetric Gram: upper-tri blocks only

  __shared__ u16 lds[2][8192];         // [A/B][128x64 bf16] = 32768 B exactly
  float* sred = (float*)&lds[0][0];    // aliased after K-loop drains

  const int tid = threadIdx.x;
  const int lane = tid & 63;
  const int wid = tid >> 6;
  const int row0 = by * 128;
  const int col0 = bx * 128;
  const int wm = wid >> 1;
  const int wn = wid & 1;

  float aco = 0.f, cco = 0.f;  // MODE 3: arg = cco + aco * g
  if (MODE == 3) {
    u32 u = __float_as_uint(scal[0]);
    u32 bits = (u & 0x80000000u) ? (u ^ 0x80000000u) : ~u;
    float vmax = __uint_as_float(bits);
    aco = -(2.0f - vmax) / vmax;
    cco = (2.0f - vmax) - shift_of(vmax);
  }

  f32x4 acc[4][4];
#pragma unroll
  for (int i = 0; i < 4; ++i)
#pragma unroll
    for (int j = 0; j < 4; ++j)
      acc[i][j] = (f32x4){0.f, 0.f, 0.f, 0.f};

  for (int k0 = 0; k0 < KDIM; k0 += 64) {
    stage64(A, Bm, row0, col0, wid, lane, k0, &lds[0][0], &lds[1][0]);
    asm volatile("s_waitcnt vmcnt(0)" ::: "memory");
    __syncthreads();
#pragma unroll
    for (int kk = 0; kk < 2; ++kk) {
      short8 af[4], bf[4];
#pragma unroll
      for (int mi = 0; mi < 4; ++mi) {
        const int R = wm * 64 + mi * 16 + (lane & 15);
        const int sl = ((kk * 4 + (lane >> 4)) ^ (lane & 7)) * 8;  // R&7 == lane&7
        af[mi] = *(const short8*)&lds[0][R * 64 + sl];
      }
#pragma unroll
      for (int ni = 0; ni < 4; ++ni) {
        const int R = wn * 64 + ni * 16 + (lane & 15);
        const int sl = ((kk * 4 + (lane >> 4)) ^ (lane & 7)) * 8;
        bf[ni] = *(const short8*)&lds[1][R * 64 + sl];
      }
#pragma unroll
      for (int mi = 0; mi < 4; ++mi)
#pragma unroll
        for (int ni = 0; ni < 4; ++ni)
          acc[mi][ni] = __builtin_amdgcn_mfma_f32_16x16x32_bf16(af[mi], bf[ni], acc[mi][ni], 0, 0, 0);
    }
    __syncthreads();
  }

  const int rl = (lane >> 4) * 4;  // C/D: row = (lane>>4)*4 + reg, col = lane&15
  const int cl = lane & 15;

  if (MODE == 0 || MODE == 1) {
    constexpr int PLANE = (MODE == 0) ? BATCH : CPAD;
    // (1) transform acc in place (ArcFace * S), accumulate CE row stats
#pragma unroll
    for (int mi = 0; mi < 4; ++mi) {
#pragma unroll
      for (int r = 0; r < 4; ++r) {
        const int gr = row0 + wm * 64 + mi * 16 + rl + r;  // uniform across 16-lane group
        const int tgt = (MODE == 0) ? label[gr] : gr;
        float se = 0.f, sm = 0.f;
#pragma unroll
        for (int ni = 0; ni < 4; ++ni) {
          const int gc = col0 + wn * 64 + ni * 16 + cl;
          float v = acc[mi][ni][r];
          float val = ((gc == tgt) ? arc_phi(v) : v) * S_SC;
          acc[mi][ni][r] = val;
          if (gc < CCLS && (MODE == 0 || gr < CCLS)) {
            se += __expf(val - 30.0f);
            sm += val;
            if (gc == tgt) rowtgt[gr] = val;  // unique writer
          }
        }
#pragma unroll
        for (int m = 1; m < 16; m <<= 1) {
          se += __shfl_xor(se, m);
          sm += __shfl_xor(sm, m);
        }
        if (cl == 0) {
          const int lr = wm * 64 + mi * 16 + rl + r;  // local row 0..127
          sred[lr * 2 + wn] = se;
          sred[256 + lr * 2 + wn] = sm;
        }
      }
    }
    __syncthreads();
    // (2) combine wn halves -> partial planes
    if (tid < 128) {
      const int gr = row0 + tid;
      if (MODE == 0 || gr < CCLS) {
        float se = sred[tid * 2] + sred[tid * 2 + 1];
        float sm = sred[256 + tid * 2] + sred[256 + tid * 2 + 1];
        pse[(size_t)bx * PLANE + gr] = se;
        psm[(size_t)bx * PLANE + gr] = sm;
      }
    }
    // (3) LDS-staged coalesced row stores, two 64-row halves (32KB each)
    float* sC = (float*)&lds[0][0];  // [64][128] f32
#pragma unroll
    for (int half = 0; half < 2; ++half) {
      __syncthreads();
      if (wm == half) {
#pragma unroll
        for (int mi = 0; mi < 4; ++mi)
#pragma unroll
          for (int ni = 0; ni < 4; ++ni)
#pragma unroll
            for (int r = 0; r < 4; ++r)
              sC[(mi * 16 + rl + r) * 128 + wn * 64 + ni * 16 + cl] = acc[mi][ni][r];
      }
      __syncthreads();
#pragma unroll
      for (int i = 0; i < 16; ++i) {
        const int lr = wid * 16 + i;
        const int gr = row0 + half * 64 + lr;
        if (MODE == 1 && gr >= CCLS) continue;
        const int gc = col0 + lane * 2;
        if (gc < CCLS) {  // CCLS even, pairs never straddle
          f32x2 v = *(const f32x2*)&sC[lr * 128 + lane * 2];
          __builtin_nontemporal_store(v, (f32x2*)(out + (size_t)gr * CCLS + gc));
        }
      }
    }
  } else {
    float lsum = 0.f;
    float lmax = -3.0e38f;
#pragma unroll
    for (int mi = 0; mi < 4; ++mi)
#pragma unroll
      for (int r = 0; r < 4; ++r) {
        const int gi = row0 + wm * 64 + mi * 16 + rl + r;
#pragma unroll
        for (int ni = 0; ni < 4; ++ni) {
          const int gj = col0 + wn * 64 + ni * 16 + cl;
          if (gi < CCLS && gj < CCLS && gi != gj) {
            float g = 2.0f * acc[mi][ni][r];
            if (MODE == 2) {
              lsum += __expf(g - 2.0f);
              lmax = fmaxf(lmax, g);
            } else {
              lsum += __expf(fmaf(aco, g, cco));
            }
          }
        }
      }
    const float wgt = (bx == by) ? 1.0f : 2.0f;  // off-diag counted twice
    lsum = wave_sum(lsum) * wgt;
    if (MODE == 2) {
#pragma unroll
      for (int off = 1; off < 64; off <<= 1) lmax = fmaxf(lmax, __shfl_xor(lmax, off));
    }
    __syncthreads();
    if (lane == 0) { sred[wid] = lsum; sred[4 + wid] = lmax; }
    __syncthreads();
    if (tid == 0) {
      float s = sred[0] + sred[1] + sred[2] + sred[3];
      atomicAdd(&scal[(MODE == 2) ? 1 : 2], s);
      if (MODE == 2) {
        float m = fmaxf(fmaxf(sred[4], sred[5]), fmaxf(sred[6], sred[7]));
        u32 b = __float_as_uint(m);
        u32 enc = (b & 0x80000000u) ? ~b : (b | 0x80000000u);
        atomicMax((u32*)&scal[0], enc);
      }
    }
  }
}

// ---------------- gather rows b >= CCLS: out2[b,:] = out2[label[b],:] (vectorized) ----------------
__global__ void gather_k(const int* __restrict__ label, float* __restrict__ out2) {
  const int b = CCLS + blockIdx.x;
  const int r = label[b];
  const f32x2* src = (const f32x2*)(out2 + (size_t)r * CCLS);
  f32x2* dst = (f32x2*)(out2 + (size_t)b * CCLS);
  for (int j = threadIdx.x; j < CCLS / 2; j += 256)
    __builtin_nontemporal_store(src[j], &dst[j]);
}

// ---------------- finalize CE from partial planes ----------------
__global__ void ce_fin_k(const float* __restrict__ pse_s, const float* __restrict__ psm_s,
                         const float* __restrict__ rowtgt_s, const float* __restrict__ pse_c,
                         const float* __restrict__ psm_c, const float* __restrict__ rowtgt_c,
                         float* __restrict__ scal) {
  const int i = blockIdx.x * 256 + threadIdx.x;
  float ls = 0.f, lc = 0.f;
  if (i < BATCH) {
    float se = 0.f, sm = 0.f;
#pragma unroll 1
    for (int p = 0; p < NCB; ++p) { se += pse_s[p * BATCH + i]; sm += psm_s[p * BATCH + i]; }
    ls = 30.0f + logf(se) - 0.9f * rowtgt_s[i] - (0.1f / (float)CCLS) * sm;
  }
  if (i < CCLS) {
    float se = 0.f, sm = 0.f;
#pragma unroll 1
    for (int p = 0; p < NCB; ++p) { se += pse_c[p * CPAD + i]; sm += psm_c[p * CPAD + i]; }
    lc = 30.0f + logf(se) - 0.9f * rowtgt_c[i] - (0.1f / (float)CCLS) * sm;
  }
  ls = wave_sum(ls);
  lc = wave_sum(lc);
  if ((threadIdx.x & 63) == 0) {
    atomicAdd(&scal[3], ls);
    atomicAdd(&scal[4], lc);
  }
}

// ---------------- finalize loss ----------------
__global__ void finalize_k(const float* __restrict__ scal, float* __restrict__ out) {
  u32 u = __float_as_uint(scal[0]);
  u32 bits = (u & 0x80000000u) ? (u ^ 0x80000000u) : ~u;
  float vmax = __uint_as_float(bits);
  float s1 = scal[1], s2 = scal[2], ces = scal[3], cec = scal[4];
  float lse1 = 2.0f + logf(s1);
  float lse2 = shift_of(vmax) + logf(s2);
  float z = lse1 - lse2 + vmax;
  float sp = (z > 20.f) ? z : log1pf(expf(z));
  out[0] = sp + 0.5f * (cec / (float)CCLS) + 0.5f * (ces / (float)BATCH);
}

extern "C" void kernel_launch(void* const* d_in, const int* in_sizes, int n_in,
                              void* d_out, int out_size, void* d_ws, size_t ws_size,
                              hipStream_t stream) {
  (void)in_sizes; (void)n_in; (void)out_size; (void)ws_size;
  const float* x = (const float*)d_in[0];
  const float* w = (const float*)d_in[1];
  const int* label = (const int*)d_in[2];
  float* out = (float*)d_out;
  float* out1 = out + 1;                                  // output_sample [B, C]
  float* out2 = out + 1 + (size_t)BATCH * CCLS;           // output_center[label] [B, C]

  char* ws = (char*)d_ws;
  size_t o = 0;
  u16* xb = (u16*)(ws + o); o += (size_t)BATCH * KDIM * 2;   // x1 bf16
  u16* wb = (u16*)(ws + o); o += (size_t)CPAD * KDIM * 2;    // w bf16 (padded)
  u16* mb = (u16*)(ws + o); o += (size_t)CPAD * KDIM * 2;    // mean bf16 (padded)
  const size_t zo = o;                                       // ---- zeroed region ----
  float* scal = (float*)(ws + o); o += 256;
  int* ecnt = (int*)(ws + o); o += (size_t)CPAD * 4;
  const size_t ze = o;                                       // ---- end zeroed ----
  int* eidx = (int*)(ws + o); o += (size_t)CPAD * EMAX * 4;
  float* rowtgt_s = (float*)(ws + o); o += (size_t)BATCH * 4;  // written before read
  float* rowtgt_c = (float*)(ws + o); o += (size_t)CPAD * 4;
  float* pse_s = (float*)(ws + o); o += (size_t)NCB * BATCH * 4;
  float* psm_s = (float*)(ws + o); o += (size_t)NCB * BATCH * 4;
  float* pse_c = (float*)(ws + o); o += (size_t)NCB * CPAD * 4;
  float* psm_c = (float*)(ws + o); o += (size_t)NCB * CPAD * 4;

  const int n4 = (int)((ze - zo) / 16);
  zero_k<<<(n4 + 255) / 256, 256, 0, stream>>>((f32x4*)(ws + zo), n4);

  norm_w_k<<<CPAD / 4, 256, 0, stream>>>(w, wb);
  norm_x_k<<<BATCH / 4, 256, 0, stream>>>(x, label, xb, ecnt, eidx);
  mean_k<<<CPAD / 4, 256, 0, stream>>>(xb, ecnt, eidx, mb);

  gemm_k<0><<<dim3(NCB, 64), 256, 0, stream>>>(xb, wb, out1, label, scal, pse_s, psm_s, rowtgt_s, 64);
  gemm_k<1><<<dim3(NCB, NCB), 256, 0, stream>>>(mb, wb, out2, label, scal, pse_c, psm_c, rowtgt_c, NCB);
  gather_k<<<BATCH - CCLS, 256, 0, stream>>>(label, out2);

  ce_fin_k<<<BATCH / 256, 256, 0, stream>>>(pse_s, psm_s, rowtgt_s, pse_c, psm_c, rowtgt_c, scal);

  gemm_k<2><<<dim3(NCB, NCB), 256, 0, stream>>>(mb, mb, nullptr, nullptr, scal, nullptr, nullptr, nullptr, NCB);
  gemm_k<3><<<dim3(NCB, NCB), 256, 0, stream>>>(mb, mb, nullptr, nullptr, scal, nullptr, nullptr, nullptr, NCB);

  finalize_k<<<1, 1, 0, stream>>>(scal, out);
}